// Round 1
// baseline (667.233 us; speedup 1.0000x reference)
//
#include <hip/hip_runtime.h>
#include <math.h>

#define NN 50000
#define EE 800000
#define RR 2
#define LL 2
#define DD 128
#define GG 64
#define CCLS 8
#define NCHUNK 49  // ceil(NN/1024)

// ---------------- workspace layout (bytes) ----------------
// xw: [2][N][D] f32, h1: [N][D] f32 (reused as layer-2 output), deg/cur: [2][N] i32,
// isd: [2][N] f32, rp: [2][N+1] i32, ci: [2][E] i32, csums: [2][49] i32,
// sums: [G][D] f32, counts: [G] i32.  Total ~81 MB.
#define OFF_XW   ((size_t)0)
#define OFF_H1   ((size_t)51200000)
#define OFF_DEG  ((size_t)76800000)
#define OFF_CUR  ((size_t)77200000)
#define OFF_ISD  ((size_t)77600000)
#define OFF_RP   ((size_t)78000000)
#define OFF_CI   ((size_t)78400128)
#define OFF_CS   ((size_t)84800128)
#define OFF_SUMS ((size_t)84800640)
#define OFF_CNT  ((size_t)84833408)

// ---------------- degree / CSR build ----------------
__global__ void k_deg(const int* __restrict__ EI, int* __restrict__ deg) {
  int idx = blockIdx.x * 256 + threadIdx.x;
  if (idx >= RR * EE) return;
  int r = idx >= EE ? 1 : 0;
  int e = idx - r * EE;
  int dst = EI[r * 2 * EE + EE + e];
  atomicAdd(&deg[r * NN + dst], 1);
}

__global__ void k_isd(const int* __restrict__ deg, float* __restrict__ isd) {
  int idx = blockIdx.x * 256 + threadIdx.x;
  if (idx >= RR * NN) return;
  isd[idx] = 1.0f / sqrtf((float)(deg[idx] + 1));
}

__global__ void k_chunksum(const int* __restrict__ deg, int* __restrict__ csums) {
  int r = blockIdx.y;
  int base = blockIdx.x * 1024;
  const int* d = deg + r * NN;
  int t = threadIdx.x;
  int s = 0;
#pragma unroll
  for (int i = 0; i < 4; ++i) {
    int idx = base + t + i * 256;
    if (idx < NN) s += d[idx];
  }
  __shared__ int sm[256];
  sm[t] = s;
  __syncthreads();
  for (int off = 128; off > 0; off >>= 1) {
    if (t < off) sm[t] += sm[t + off];
    __syncthreads();
  }
  if (t == 0) csums[r * NCHUNK + blockIdx.x] = sm[0];
}

__global__ void k_scancsums(int* csums) {
  int r = threadIdx.x;
  if (r < RR) {
    int run = 0;
    for (int i = 0; i < NCHUNK; ++i) {
      int v = csums[r * NCHUNK + i];
      csums[r * NCHUNK + i] = run;
      run += v;
    }
  }
}

__global__ void k_scanfinal(const int* __restrict__ deg, const int* __restrict__ csums,
                            int* __restrict__ rp) {
  int r = blockIdx.y, t = threadIdx.x;
  int base = blockIdx.x * 1024;
  const int* d = deg + r * NN;
  int v[4];
  int s = 0;
#pragma unroll
  for (int i = 0; i < 4; ++i) {
    int idx = base + t * 4 + i;
    v[i] = (idx < NN) ? d[idx] : 0;
    s += v[i];
  }
  __shared__ int sm[256];
  sm[t] = s;
  __syncthreads();
  for (int off = 1; off < 256; off <<= 1) {
    int tv = (t >= off) ? sm[t - off] : 0;
    __syncthreads();
    sm[t] += tv;
    __syncthreads();
  }
  int excl = sm[t] - s;
  int run = csums[r * NCHUNK + blockIdx.x] + excl;
  int* out = rp + r * (NN + 1);
#pragma unroll
  for (int i = 0; i < 4; ++i) {
    int idx = base + t * 4 + i;
    if (idx < NN) {
      out[idx] = run;
      run += v[i];
      if (idx == NN - 1) out[NN] = run;
    }
  }
}

__global__ void k_fill(const int* __restrict__ EI, const int* __restrict__ rp,
                       int* __restrict__ cur, int* __restrict__ ci) {
  int idx = blockIdx.x * 256 + threadIdx.x;
  if (idx >= RR * EE) return;
  int r = idx >= EE ? 1 : 0;
  int e = idx - r * EE;
  int src = EI[r * 2 * EE + e];
  int dst = EI[r * 2 * EE + EE + e];
  int pos = atomicAdd(&cur[r * NN + dst], 1);
  ci[r * EE + rp[r * (NN + 1) + dst] + pos] = src;
}

// ---------------- dense GEMM: Y[r] = X @ W[r]  (X:[N,128], W:[128,128]) ----------------
// block 256 threads, tile 64 rows x 128 cols, K split in two 64-halves.
// Bs layout: [cg:16][k:64][j:8] with per-cg stride 516 floats (pad 4 -> bank spread).
// As layout: [k:64][row:64] (transposed for b128 reads).
__global__ __launch_bounds__(256) void k_gemm(const float* __restrict__ X,
                                              const float* __restrict__ Wl,
                                              float* __restrict__ Y) {
  __shared__ float Bs[16 * 516];
  __shared__ float As[64 * 64];
  const int r = blockIdx.y;
  const float* W = Wl + r * (DD * DD);
  float* Yr = Y + (size_t)r * NN * DD;
  const int row0 = blockIdx.x * 64;
  const int t = threadIdx.x;
  const int rg = t & 15, cg = t >> 4;
  const int arow = t & 63, akq = t >> 6;
  float acc[4][8];
#pragma unroll
  for (int i = 0; i < 4; ++i)
#pragma unroll
    for (int j = 0; j < 8; ++j) acc[i][j] = 0.f;

  for (int h = 0; h < 2; ++h) {
    __syncthreads();
    // stage W half: k in [h*64, h*64+64)
#pragma unroll
    for (int q = 0; q < 8; ++q) {
      int f4 = (t + 256 * q) * 4;
      int k = f4 >> 7;
      int c = f4 & 127;
      float4 v = *(const float4*)(W + (size_t)(h * 64 + k) * DD + c);
      *(float4*)(Bs + (c >> 3) * 516 + k * 8 + (c & 7)) = v;
    }
    // stage A half, transposed
    {
      int grow = row0 + arow;
      float4 v0, v1, v2, v3;
      if (grow < NN) {
        const float* xp = X + (size_t)grow * DD + h * 64 + akq * 16;
        v0 = *(const float4*)(xp);
        v1 = *(const float4*)(xp + 4);
        v2 = *(const float4*)(xp + 8);
        v3 = *(const float4*)(xp + 12);
      } else {
        v0 = v1 = v2 = v3 = make_float4(0.f, 0.f, 0.f, 0.f);
      }
      float tmp[16] = {v0.x, v0.y, v0.z, v0.w, v1.x, v1.y, v1.z, v1.w,
                       v2.x, v2.y, v2.z, v2.w, v3.x, v3.y, v3.z, v3.w};
#pragma unroll
      for (int i = 0; i < 16; ++i) As[(akq * 16 + i) * 64 + arow] = tmp[i];
    }
    __syncthreads();
#pragma unroll 8
    for (int kk = 0; kk < 64; ++kk) {
      float4 a = *(const float4*)(As + kk * 64 + rg * 4);
      float4 b0 = *(const float4*)(Bs + cg * 516 + kk * 8);
      float4 b1 = *(const float4*)(Bs + cg * 516 + kk * 8 + 4);
      float av[4] = {a.x, a.y, a.z, a.w};
      float bv[8] = {b0.x, b0.y, b0.z, b0.w, b1.x, b1.y, b1.z, b1.w};
#pragma unroll
      for (int i = 0; i < 4; ++i)
#pragma unroll
        for (int j = 0; j < 8; ++j) acc[i][j] = fmaf(av[i], bv[j], acc[i][j]);
    }
  }
#pragma unroll
  for (int i = 0; i < 4; ++i) {
    int grow = row0 + rg * 4 + i;
    if (grow < NN) {
      float* yp = Yr + (size_t)grow * DD + cg * 8;
      *(float4*)(yp) = make_float4(acc[i][0], acc[i][1], acc[i][2], acc[i][3]);
      *(float4*)(yp + 4) = make_float4(acc[i][4], acc[i][5], acc[i][6], acc[i][7]);
    }
  }
}

// ---------------- aggregation: out[i] = sum_r (A_r-gather of xw_r + selfloop + b_r) ----------------
__global__ __launch_bounds__(128) void k_agg(const float* __restrict__ xw,
                                             const int* __restrict__ rp,
                                             const int* __restrict__ ci,
                                             const float* __restrict__ isd,
                                             const float* __restrict__ bias,
                                             float* __restrict__ hout, int relu_flag) {
  int i = blockIdx.x;
  int c = threadIdx.x;
  float acc = bias[c] + bias[DD + c];
#pragma unroll
  for (int r = 0; r < RR; ++r) {
    const float* xwr = xw + (size_t)r * NN * DD;
    const float* isdr = isd + r * NN;
    const int* cir = ci + r * EE;
    float di = isdr[i];
    acc += xwr[(size_t)i * DD + c] * (di * di);  // self loop: 1/deg
    int e0 = rp[r * (NN + 1) + i];
    int e1 = rp[r * (NN + 1) + i + 1];
    int e = e0;
    for (; e + 4 <= e1; e += 4) {
      int s0 = cir[e], s1 = cir[e + 1], s2 = cir[e + 2], s3 = cir[e + 3];
      float w0 = isdr[s0], w1 = isdr[s1], w2 = isdr[s2], w3 = isdr[s3];
      float x0 = xwr[(size_t)s0 * DD + c];
      float x1 = xwr[(size_t)s1 * DD + c];
      float x2 = xwr[(size_t)s2 * DD + c];
      float x3 = xwr[(size_t)s3 * DD + c];
      acc += (di * w0) * x0;
      acc += (di * w1) * x1;
      acc += (di * w2) * x2;
      acc += (di * w3) * x3;
    }
    for (; e < e1; ++e) {
      int s = cir[e];
      acc += (di * isdr[s]) * xwr[(size_t)s * DD + c];
    }
  }
  hout[(size_t)i * DD + c] = relu_flag ? fmaxf(acc, 0.f) : acc;
}

// ---------------- pooling (batch ids sorted) ----------------
__global__ __launch_bounds__(128) void k_pool(const float* __restrict__ h,
                                              const int* __restrict__ batch,
                                              float* __restrict__ sums,
                                              int* __restrict__ counts) {
  int c = threadIdx.x;
  int n0 = blockIdx.x * 256;
  int n1 = n0 + 256;
  if (n1 > NN) n1 = NN;
  if (n0 >= NN) return;
  float acc = 0.f;
  int cnt = 0;
  int g = batch[n0];
  for (int n = n0; n < n1; ++n) {
    int gn = batch[n];
    if (gn != g) {
      atomicAdd(&sums[g * DD + c], acc);
      if (c == 0) atomicAdd(&counts[g], cnt);
      acc = 0.f;
      cnt = 0;
      g = gn;
    }
    acc += h[(size_t)n * DD + c];
    cnt++;
  }
  atomicAdd(&sums[g * DD + c], acc);
  if (c == 0) atomicAdd(&counts[g], cnt);
}

__global__ __launch_bounds__(512) void k_final(const float* __restrict__ sums,
                                               const int* __restrict__ counts,
                                               const float* __restrict__ lin_w,
                                               const float* __restrict__ lin_b,
                                               float* __restrict__ out) {
  int t = threadIdx.x;  // 512 = 64 graphs x 8 classes
  int g = t >> 3, co = t & 7;
  float cnt = (float)counts[g];
  if (cnt < 1.f) cnt = 1.f;
  float inv = 1.f / cnt;
  float v = lin_b[co];
  for (int d = 0; d < DD; ++d) v += (sums[g * DD + d] * inv) * lin_w[d * CCLS + co];
  out[t] = v;
}

extern "C" void kernel_launch(void* const* d_in, const int* in_sizes, int n_in,
                              void* d_out, int out_size, void* d_ws, size_t ws_size,
                              hipStream_t stream) {
  (void)in_sizes; (void)n_in; (void)out_size; (void)ws_size;
  const float* x     = (const float*)d_in[0];
  const float* W     = (const float*)d_in[1];
  const float* b     = (const float*)d_in[2];
  const float* lin_w = (const float*)d_in[3];
  const float* lin_b = (const float*)d_in[4];
  const int*   EI    = (const int*)d_in[5];
  const int*   batch = (const int*)d_in[6];
  float* out = (float*)d_out;

  char* ws = (char*)d_ws;
  float* xw    = (float*)(ws + OFF_XW);
  float* h1    = (float*)(ws + OFF_H1);
  int*   deg   = (int*)(ws + OFF_DEG);
  int*   cur   = (int*)(ws + OFF_CUR);
  float* isd   = (float*)(ws + OFF_ISD);
  int*   rp    = (int*)(ws + OFF_RP);
  int*   ci    = (int*)(ws + OFF_CI);
  int*   csums = (int*)(ws + OFF_CS);
  float* sums  = (float*)(ws + OFF_SUMS);
  int*   counts= (int*)(ws + OFF_CNT);

  (void)hipMemsetAsync(deg, 0, RR * NN * 4, stream);
  (void)hipMemsetAsync(cur, 0, RR * NN * 4, stream);
  (void)hipMemsetAsync(sums, 0, GG * DD * 4, stream);
  (void)hipMemsetAsync(counts, 0, GG * 4, stream);

  k_deg<<<(RR * EE + 255) / 256, 256, 0, stream>>>(EI, deg);
  k_isd<<<(RR * NN + 255) / 256, 256, 0, stream>>>(deg, isd);
  k_chunksum<<<dim3(NCHUNK, RR), 256, 0, stream>>>(deg, csums);
  k_scancsums<<<1, 64, 0, stream>>>(csums);
  k_scanfinal<<<dim3(NCHUNK, RR), 256, 0, stream>>>(deg, csums, rp);
  k_fill<<<(RR * EE + 255) / 256, 256, 0, stream>>>(EI, rp, cur, ci);

  for (int l = 0; l < LL; ++l) {
    const float* hin = (l == 0) ? x : h1;
    k_gemm<<<dim3((NN + 63) / 64, RR), 256, 0, stream>>>(hin, W + (size_t)l * RR * DD * DD, xw);
    k_agg<<<NN, DD, 0, stream>>>(xw, rp, ci, isd, b + (size_t)l * RR * DD, h1,
                                 (l < LL - 1) ? 1 : 0);
  }
  k_pool<<<(NN + 255) / 256, 128, 0, stream>>>(h1, batch, sums, counts);
  k_final<<<1, GG * CCLS, 0, stream>>>(sums, counts, lin_w, lin_b, out);
}

// Round 2
// 505.431 us; speedup vs baseline: 1.3201x; 1.3201x over previous
//
#include <hip/hip_runtime.h>
#include <math.h>

#define NN 50000
#define EE 800000
#define RR 2
#define LL 2
#define DD 128
#define GG 64
#define CCLS 8
#define NCHUNK 49  // ceil(NN/1024)

typedef unsigned int uint;
typedef unsigned short ushort;
typedef short bf16x8 __attribute__((ext_vector_type(8)));
typedef float f32x4 __attribute__((ext_vector_type(4)));

// ---------------- workspace layout (bytes) ----------------
// xw(bf16 packed): [2][N][64] uint, h1(bf16 packed): [N][64] uint,
// WbfT: [L][R][128][128] bf16, isd: [2][N] f32, rp: [2][N+1] i32, ci: [2][E] i32,
// csums, zero-region {deg[2N], cur[2N], sums[G*D] f32, counts[G]}
#define OFF_XW    ((size_t)0)
#define OFF_H1    ((size_t)25600000)
#define OFF_WBT   ((size_t)38400000)
#define OFF_ISD   ((size_t)38531072)
#define OFF_RP    ((size_t)38931072)
#define OFF_CI    ((size_t)39331136)
#define OFF_CS    ((size_t)45731136)
#define OFF_ZERO  ((size_t)45731584)
// zero region internal offsets (bytes)
#define ZO_DEG 0
#define ZO_CUR 400000
#define ZO_SUM 800000
#define ZO_CNT 832768
#define ZERO_BYTES 833024

static __device__ __forceinline__ ushort f2b(float f) {
  uint u = __float_as_uint(f);
  uint r = (u + 0x7fffu + ((u >> 16) & 1u)) >> 16;
  return (ushort)r;
}
static __device__ __forceinline__ float blo(uint u) { return __uint_as_float(u << 16); }
static __device__ __forceinline__ float bhi(uint u) { return __uint_as_float(u & 0xffff0000u); }

// ---------------- W prep: fp32 W[l][r][k][n] -> bf16 WbfT[l][r][n][k] ----------------
__global__ __launch_bounds__(256) void k_wprep(const float* __restrict__ W,
                                               ushort* __restrict__ WT) {
  int idx = blockIdx.x * 256 + threadIdx.x;           // 65536 total
  int lr = idx >> 14;
  int rem = idx & 16383;
  int n = rem >> 7, k = rem & 127;
  WT[lr * 16384 + n * 128 + k] = f2b(W[lr * 16384 + k * 128 + n]);
}

// ---------------- degree / CSR build ----------------
__global__ __launch_bounds__(256) void k_deg(const int* __restrict__ EI, int* __restrict__ deg) {
  int r = blockIdx.y;
  int e4 = (blockIdx.x * 256 + threadIdx.x) * 4;
  if (e4 >= EE) return;
  int4 d = *(const int4*)(EI + (size_t)r * 2 * EE + EE + e4);
  int* dr = deg + r * NN;
  atomicAdd(&dr[d.x], 1);
  atomicAdd(&dr[d.y], 1);
  atomicAdd(&dr[d.z], 1);
  atomicAdd(&dr[d.w], 1);
}

__global__ __launch_bounds__(256) void k_isd(const int* __restrict__ deg, float* __restrict__ isd) {
  int idx = blockIdx.x * 256 + threadIdx.x;
  if (idx >= RR * NN) return;
  isd[idx] = 1.0f / sqrtf((float)(deg[idx] + 1));
}

__global__ void k_chunksum(const int* __restrict__ deg, int* __restrict__ csums) {
  int r = blockIdx.y;
  int base = blockIdx.x * 1024;
  const int* d = deg + r * NN;
  int t = threadIdx.x;
  int s = 0;
#pragma unroll
  for (int i = 0; i < 4; ++i) {
    int idx = base + t + i * 256;
    if (idx < NN) s += d[idx];
  }
  __shared__ int sm[256];
  sm[t] = s;
  __syncthreads();
  for (int off = 128; off > 0; off >>= 1) {
    if (t < off) sm[t] += sm[t + off];
    __syncthreads();
  }
  if (t == 0) csums[r * NCHUNK + blockIdx.x] = sm[0];
}

__global__ void k_scancsums(int* csums) {
  int r = threadIdx.x;
  if (r < RR) {
    int run = 0;
    for (int i = 0; i < NCHUNK; ++i) {
      int v = csums[r * NCHUNK + i];
      csums[r * NCHUNK + i] = run;
      run += v;
    }
  }
}

__global__ void k_scanfinal(const int* __restrict__ deg, const int* __restrict__ csums,
                            int* __restrict__ rp) {
  int r = blockIdx.y, t = threadIdx.x;
  int base = blockIdx.x * 1024;
  const int* d = deg + r * NN;
  int v[4];
  int s = 0;
#pragma unroll
  for (int i = 0; i < 4; ++i) {
    int idx = base + t * 4 + i;
    v[i] = (idx < NN) ? d[idx] : 0;
    s += v[i];
  }
  __shared__ int sm[256];
  sm[t] = s;
  __syncthreads();
  for (int off = 1; off < 256; off <<= 1) {
    int tv = (t >= off) ? sm[t - off] : 0;
    __syncthreads();
    sm[t] += tv;
    __syncthreads();
  }
  int excl = sm[t] - s;
  int run = csums[r * NCHUNK + blockIdx.x] + excl;
  int* out = rp + r * (NN + 1);
#pragma unroll
  for (int i = 0; i < 4; ++i) {
    int idx = base + t * 4 + i;
    if (idx < NN) {
      out[idx] = run;
      run += v[i];
      if (idx == NN - 1) out[NN] = run;
    }
  }
}

__global__ __launch_bounds__(256) void k_fill(const int* __restrict__ EI, const int* __restrict__ rp,
                                              int* __restrict__ cur, int* __restrict__ ci) {
  int r = blockIdx.y;
  int e4 = (blockIdx.x * 256 + threadIdx.x) * 4;
  if (e4 >= EE) return;
  int4 s4 = *(const int4*)(EI + (size_t)r * 2 * EE + e4);
  int4 d4 = *(const int4*)(EI + (size_t)r * 2 * EE + EE + e4);
  int* curr = cur + r * NN;
  const int* rpr = rp + r * (NN + 1);
  int* cir = ci + (size_t)r * EE;
  int p;
  p = atomicAdd(&curr[d4.x], 1); cir[rpr[d4.x] + p] = s4.x;
  p = atomicAdd(&curr[d4.y], 1); cir[rpr[d4.y] + p] = s4.y;
  p = atomicAdd(&curr[d4.z], 1); cir[rpr[d4.z] + p] = s4.z;
  p = atomicAdd(&curr[d4.w], 1); cir[rpr[d4.w] + p] = s4.w;
}

// ---------------- MFMA GEMM: xw[r][m][n] = X[m][:] @ W[r][:][n], bf16 out ----------------
// Block: 256 thr (4 waves), tile M=128 (32/wave), N=128, K=128 in two 64-halves.
// MFMA arrangement: D[i=n][j=m] = sum_k WT[n][k] * X[m][k]
//   A-operand = WT frag: A[i=lane&15][k=quad*8+j]   (WT rows contiguous in k)
//   B-operand = X  frag: B[k=quad*8+j][j=lane&15]   (X rows contiguous in k)
//   C/D: col(lane&15)=m, row(quad*4+reg)=n -> 4 consecutive n per lane -> uint2 store
#define AL_S 72    // 64+8 bf16: 144 B row stride (16B-aligned, conflict-free)
#define WT_S 136   // 128+8 bf16: 272 B row stride
template <int IN_BF16>
__global__ __launch_bounds__(256) void k_gemm(const void* __restrict__ Xv,
                                              const ushort* __restrict__ WTg,
                                              uint* __restrict__ Y) {
  __shared__ ushort WTl[128 * WT_S];
  __shared__ ushort Al[128 * AL_S];
  const int r = blockIdx.y;
  const int m0b = blockIdx.x * 128;
  const int t = threadIdx.x;
  const int w = t >> 6, L = t & 63, q = L >> 4, ln = L & 15;
  uint* Yr = Y + (size_t)r * NN * 64;
  const ushort* WTr = WTg + (size_t)r * 16384;

  // stage WT: 16384 bf16, 8x uint4 per thread
#pragma unroll
  for (int i = 0; i < 8; ++i) {
    int g = t + i * 256;          // group of 8 bf16
    int n = g >> 4, k0 = (g & 15) * 8;
    *(uint4*)(&WTl[n * WT_S + k0]) = *(const uint4*)(WTr + n * 128 + k0);
  }

  f32x4 acc[2][8];
#pragma unroll
  for (int mt = 0; mt < 2; ++mt)
#pragma unroll
    for (int nt = 0; nt < 8; ++nt) {
      acc[mt][nt][0] = 0.f; acc[mt][nt][1] = 0.f;
      acc[mt][nt][2] = 0.f; acc[mt][nt][3] = 0.f;
    }

  for (int hh = 0; hh < 2; ++hh) {
    __syncthreads();
    // stage A half: rows 128 x 64 cols (k in [hh*64, hh*64+64))
    {
      int row = t >> 1, ch = t & 1;
      int gm = m0b + row;
      ushort* dst = &Al[row * AL_S + ch * 32];
      if (gm < NN) {
        if (IN_BF16) {
          const uint4* xp = (const uint4*)((const ushort*)Xv + (size_t)gm * 128 + hh * 64 + ch * 32);
#pragma unroll
          for (int j = 0; j < 4; ++j) ((uint4*)dst)[j] = xp[j];
        } else {
          const float4* xp = (const float4*)((const float*)Xv + (size_t)gm * 128 + hh * 64 + ch * 32);
          ushort tmp[32];
#pragma unroll
          for (int j = 0; j < 8; ++j) {
            float4 v = xp[j];
            tmp[j * 4 + 0] = f2b(v.x); tmp[j * 4 + 1] = f2b(v.y);
            tmp[j * 4 + 2] = f2b(v.z); tmp[j * 4 + 3] = f2b(v.w);
          }
#pragma unroll
          for (int j = 0; j < 4; ++j) ((uint4*)dst)[j] = ((uint4*)tmp)[j];
        }
      } else {
        uint4 z = make_uint4(0, 0, 0, 0);
#pragma unroll
        for (int j = 0; j < 4; ++j) ((uint4*)dst)[j] = z;
      }
    }
    __syncthreads();
#pragma unroll
    for (int kk = 0; kk < 2; ++kk) {
      bf16x8 b0 = *(const bf16x8*)(&Al[(w * 32 + ln) * AL_S + kk * 32 + q * 8]);
      bf16x8 b1 = *(const bf16x8*)(&Al[(w * 32 + 16 + ln) * AL_S + kk * 32 + q * 8]);
#pragma unroll
      for (int nt = 0; nt < 8; ++nt) {
        bf16x8 a = *(const bf16x8*)(&WTl[(nt * 16 + ln) * WT_S + hh * 64 + kk * 32 + q * 8]);
        acc[0][nt] = __builtin_amdgcn_mfma_f32_16x16x32_bf16(a, b0, acc[0][nt], 0, 0, 0);
        acc[1][nt] = __builtin_amdgcn_mfma_f32_16x16x32_bf16(a, b1, acc[1][nt], 0, 0, 0);
      }
    }
  }
  // epilogue: lane holds D for m = m0b + w*32 + mt*16 + ln, n = nt*16 + q*4 + reg
#pragma unroll
  for (int mt = 0; mt < 2; ++mt) {
    int m = m0b + w * 32 + mt * 16 + ln;
    if (m < NN) {
      uint* yp = Yr + (size_t)m * 64 + q * 2;
#pragma unroll
      for (int nt = 0; nt < 8; ++nt) {
        f32x4 v = acc[mt][nt];
        uint lo = (uint)f2b(v[0]) | ((uint)f2b(v[1]) << 16);
        uint hi = (uint)f2b(v[2]) | ((uint)f2b(v[3]) << 16);
        *(uint2*)(yp + nt * 8) = make_uint2(lo, hi);
      }
    }
  }
}

// ---------------- aggregation: 1 wave per node, 2 channels/lane (packed bf16) ----------------
__global__ __launch_bounds__(256) void k_agg(const uint* __restrict__ xw,
                                             const int* __restrict__ rp,
                                             const int* __restrict__ ci,
                                             const float* __restrict__ isd,
                                             const float* __restrict__ bias,
                                             uint* __restrict__ hout, int relu_flag) {
  int w = threadIdx.x >> 6;
  int lane = threadIdx.x & 63;
  int i = blockIdx.x * 4 + w;
  float aLo = bias[lane * 2] + bias[DD + lane * 2];
  float aHi = bias[lane * 2 + 1] + bias[DD + lane * 2 + 1];
#pragma unroll
  for (int r = 0; r < RR; ++r) {
    const uint* xwr = xw + (size_t)r * NN * 64;
    const float* isdr = isd + r * NN;
    const int* cir = ci + (size_t)r * EE;
    float di = isdr[i];
    uint us = xwr[(size_t)i * 64 + lane];
    float dd = di * di;
    aLo += blo(us) * dd;
    aHi += bhi(us) * dd;
    int e0 = rp[r * (NN + 1) + i];
    int e1 = rp[r * (NN + 1) + i + 1];
    int e = e0;
    for (; e + 8 <= e1; e += 8) {
      int s[8];
      uint u[8];
      float wt[8];
#pragma unroll
      for (int j = 0; j < 8; ++j) s[j] = cir[e + j];
#pragma unroll
      for (int j = 0; j < 8; ++j) u[j] = xwr[(size_t)s[j] * 64 + lane];
#pragma unroll
      for (int j = 0; j < 8; ++j) wt[j] = isdr[s[j]] * di;
#pragma unroll
      for (int j = 0; j < 8; ++j) {
        aLo += blo(u[j]) * wt[j];
        aHi += bhi(u[j]) * wt[j];
      }
    }
    for (; e < e1; ++e) {
      int s = cir[e];
      float wt = isdr[s] * di;
      uint u = xwr[(size_t)s * 64 + lane];
      aLo += blo(u) * wt;
      aHi += bhi(u) * wt;
    }
  }
  if (relu_flag) {
    aLo = fmaxf(aLo, 0.f);
    aHi = fmaxf(aHi, 0.f);
  }
  hout[(size_t)i * 64 + lane] = (uint)f2b(aLo) | ((uint)f2b(aHi) << 16);
}

// ---------------- pooling (batch ids sorted), packed bf16 input ----------------
__global__ __launch_bounds__(64) void k_pool(const uint* __restrict__ h,
                                             const int* __restrict__ batch,
                                             float* __restrict__ sums,
                                             int* __restrict__ counts) {
  int lane = threadIdx.x;
  int n0 = blockIdx.x * 256;
  int n1 = n0 + 256;
  if (n1 > NN) n1 = NN;
  if (n0 >= NN) return;
  float aLo = 0.f, aHi = 0.f;
  int cnt = 0;
  int g = batch[n0];
  for (int n = n0; n < n1; ++n) {
    int gn = batch[n];
    if (gn != g) {
      atomicAdd(&sums[g * DD + lane * 2], aLo);
      atomicAdd(&sums[g * DD + lane * 2 + 1], aHi);
      if (lane == 0) atomicAdd(&counts[g], cnt);
      aLo = 0.f; aHi = 0.f; cnt = 0;
      g = gn;
    }
    uint u = h[(size_t)n * 64 + lane];
    aLo += blo(u);
    aHi += bhi(u);
    cnt++;
  }
  atomicAdd(&sums[g * DD + lane * 2], aLo);
  atomicAdd(&sums[g * DD + lane * 2 + 1], aHi);
  if (lane == 0) atomicAdd(&counts[g], cnt);
}

__global__ __launch_bounds__(512) void k_final(const float* __restrict__ sums,
                                               const int* __restrict__ counts,
                                               const float* __restrict__ lin_w,
                                               const float* __restrict__ lin_b,
                                               float* __restrict__ out) {
  int t = threadIdx.x;  // 512 = 64 graphs x 8 classes
  int g = t >> 3, co = t & 7;
  float cnt = (float)counts[g];
  if (cnt < 1.f) cnt = 1.f;
  float inv = 1.f / cnt;
  float v = lin_b[co];
  for (int d = 0; d < DD; ++d) v += (sums[g * DD + d] * inv) * lin_w[d * CCLS + co];
  out[t] = v;
}

extern "C" void kernel_launch(void* const* d_in, const int* in_sizes, int n_in,
                              void* d_out, int out_size, void* d_ws, size_t ws_size,
                              hipStream_t stream) {
  (void)in_sizes; (void)n_in; (void)out_size; (void)ws_size;
  const float* x     = (const float*)d_in[0];
  const float* W     = (const float*)d_in[1];
  const float* b     = (const float*)d_in[2];
  const float* lin_w = (const float*)d_in[3];
  const float* lin_b = (const float*)d_in[4];
  const int*   EI    = (const int*)d_in[5];
  const int*   batch = (const int*)d_in[6];
  float* out = (float*)d_out;

  char* ws = (char*)d_ws;
  uint*   xw    = (uint*)(ws + OFF_XW);
  uint*   h1    = (uint*)(ws + OFF_H1);
  ushort* WbfT  = (ushort*)(ws + OFF_WBT);
  float*  isd   = (float*)(ws + OFF_ISD);
  int*    rp    = (int*)(ws + OFF_RP);
  int*    ci    = (int*)(ws + OFF_CI);
  int*    csums = (int*)(ws + OFF_CS);
  char*   zb    = ws + OFF_ZERO;
  int*    deg   = (int*)(zb + ZO_DEG);
  int*    cur   = (int*)(zb + ZO_CUR);
  float*  sums  = (float*)(zb + ZO_SUM);
  int*    counts= (int*)(zb + ZO_CNT);

  (void)hipMemsetAsync(zb, 0, ZERO_BYTES, stream);

  k_wprep<<<256, 256, 0, stream>>>(W, WbfT);
  k_deg<<<dim3((EE / 4 + 255) / 256, RR), 256, 0, stream>>>(EI, deg);
  k_isd<<<(RR * NN + 255) / 256, 256, 0, stream>>>(deg, isd);
  k_chunksum<<<dim3(NCHUNK, RR), 256, 0, stream>>>(deg, csums);
  k_scancsums<<<1, 64, 0, stream>>>(csums);
  k_scanfinal<<<dim3(NCHUNK, RR), 256, 0, stream>>>(deg, csums, rp);
  k_fill<<<dim3((EE / 4 + 255) / 256, RR), 256, 0, stream>>>(EI, rp, cur, ci);

  for (int l = 0; l < LL; ++l) {
    const ushort* WTl_g = WbfT + (size_t)l * RR * DD * DD;
    if (l == 0)
      k_gemm<0><<<dim3((NN + 127) / 128, RR), 256, 0, stream>>>((const void*)x, WTl_g, xw);
    else
      k_gemm<1><<<dim3((NN + 127) / 128, RR), 256, 0, stream>>>((const void*)h1, WTl_g, xw);
    k_agg<<<(NN + 3) / 4, 256, 0, stream>>>(xw, rp, ci, isd, b + (size_t)l * RR * DD, h1,
                                            (l < LL - 1) ? 1 : 0);
  }
  k_pool<<<(NN + 255) / 256, 64, 0, stream>>>(h1, batch, sums, counts);
  k_final<<<1, GG * CCLS, 0, stream>>>(sums, counts, lin_w, lin_b, out);
}

// Round 3
// 370.417 us; speedup vs baseline: 1.8013x; 1.3645x over previous
//
#include <hip/hip_runtime.h>
#include <math.h>

#define NN 50000
#define EE 800000
#define RR 2
#define LL 2
#define DD 128
#define GG 64
#define CCLS 8
#define NBUK 196     // buckets of 256 dst nodes: bucket = dst >> 8
#define BCAP 6144    // max edges per bucket (mean 4096, sigma 64)

typedef unsigned int uint;
typedef unsigned short ushort;
typedef short bf16x8 __attribute__((ext_vector_type(8)));
typedef float f32x4 __attribute__((ext_vector_type(4)));

// ---------------- workspace layout (bytes) ----------------
#define OFF_XW    ((size_t)0)           // [2][N][64] uint (packed bf16)   25,600,000
#define OFF_H1    ((size_t)25600000)    // [N][64] uint                    12,800,000
#define OFF_WBT   ((size_t)38400000)    // [L][R][128][128] bf16              131,072
#define OFF_ISD   ((size_t)38531072)    // [2][N] f32                         400,000
#define OFF_RP    ((size_t)38931072)    // [2][N+1] i32                       400,064
#define OFF_CI    ((size_t)39331136)    // [2][E] i32                       6,400,000
#define OFF_BD    ((size_t)45731136)    // [2][196][6144] uint2            19,267,584
#define OFF_BB    ((size_t)64998720)    // [2][196] i32 bucket bases            1,600
#define OFF_ZERO  ((size_t)65000320)
// zero region internal offsets (bytes)
#define ZO_GCUR 0        // [2][196] i32 bucket counters (1568 B)
#define ZO_SUM  1600     // [G][D] f32 (32768 B)
#define ZO_CNT  34368    // [G] i32 (256 B)
#define ZERO_BYTES 34624

static __device__ __forceinline__ ushort f2b(float f) {
  uint u = __float_as_uint(f);
  uint r = (u + 0x7fffu + ((u >> 16) & 1u)) >> 16;
  return (ushort)r;
}
static __device__ __forceinline__ float blo(uint u) { return __uint_as_float(u << 16); }
static __device__ __forceinline__ float bhi(uint u) { return __uint_as_float(u & 0xffff0000u); }

// ---------------- W prep: fp32 W[l][r][k][n] -> bf16 WbfT[l][r][n][k] ----------------
__global__ __launch_bounds__(256) void k_wprep(const float* __restrict__ W,
                                               ushort* __restrict__ WT) {
  int idx = blockIdx.x * 256 + threadIdx.x;  // 65536 total
  int lr = idx >> 14;
  int rem = idx & 16383;
  int n = rem >> 7, k = rem & 127;
  WT[lr * 16384 + n * 128 + k] = f2b(W[lr * 16384 + k * 128 + n]);
}

// ---------------- phase 1: partition edges into dst buckets (coalesced) ----------------
__global__ __launch_bounds__(256) void k_part(const int* __restrict__ EI,
                                              int* __restrict__ gcur,
                                              uint2* __restrict__ bdata) {
  __shared__ int hist[256];   // bucket counts, then reused as stage-exclusive offsets
  __shared__ int sbase[256];  // scan scratch
  __shared__ int gbase[256];  // global reservation base per bucket
  __shared__ int lcur[256];
  __shared__ uint2 stage[4096];
  const int r = blockIdx.y;
  const int t = threadIdx.x;
  const int e0 = blockIdx.x * 4096;
  const int cnt = min(4096, EE - e0);
  hist[t] = 0;
  lcur[t] = 0;
  __syncthreads();

  int src[16], dst[16];
  bool val[4];
#pragma unroll
  for (int j = 0; j < 4; ++j) {
    int i4 = (j * 256 + t) * 4;
    val[j] = (i4 < cnt);
    if (val[j]) {
      int4 s4 = *(const int4*)(EI + (size_t)r * 2 * EE + e0 + i4);
      int4 d4 = *(const int4*)(EI + (size_t)r * 2 * EE + EE + e0 + i4);
      src[j * 4 + 0] = s4.x; src[j * 4 + 1] = s4.y; src[j * 4 + 2] = s4.z; src[j * 4 + 3] = s4.w;
      dst[j * 4 + 0] = d4.x; dst[j * 4 + 1] = d4.y; dst[j * 4 + 2] = d4.z; dst[j * 4 + 3] = d4.w;
#pragma unroll
      for (int i = 0; i < 4; ++i) atomicAdd(&hist[dst[j * 4 + i] >> 8], 1);
    }
  }
  __syncthreads();
  int hv = hist[t];
  if (t < NBUK && hv > 0)
    gbase[t] = atomicAdd(&gcur[r * NBUK + t], hv);
  else
    gbase[t] = 0;
  sbase[t] = hv;
  __syncthreads();
  for (int off = 1; off < 256; off <<= 1) {
    int u = (t >= off) ? sbase[t - off] : 0;
    __syncthreads();
    sbase[t] += u;
    __syncthreads();
  }
  int incl = sbase[t];
  hist[t] = incl - hv;  // exclusive stage offset
  __syncthreads();
#pragma unroll
  for (int j = 0; j < 4; ++j) {
    if (val[j]) {
#pragma unroll
      for (int i = 0; i < 4; ++i) {
        int d = dst[j * 4 + i];
        int b = d >> 8;
        int p = atomicAdd(&lcur[b], 1);
        stage[hist[b] + p] = make_uint2((uint)src[j * 4 + i], (uint)d);
      }
    }
  }
  __syncthreads();
  for (int s = t; s < cnt; s += 256) {
    uint2 pr = stage[s];
    int b = (int)(pr.y >> 8);
    bdata[(size_t)(r * NBUK + b) * BCAP + gbase[b] + (s - hist[b])] = pr;
  }
}

// ---------------- phase 2: scan bucket counts -> bases ----------------
__global__ __launch_bounds__(512) void k_bscan(const int* __restrict__ gcur,
                                               int* __restrict__ bbase,
                                               int* __restrict__ rp) {
  __shared__ int sm[512];
  int t = threadIdx.x;
  int r = t >> 8, j = t & 255;
  int v = (j < NBUK) ? gcur[r * NBUK + j] : 0;
  sm[t] = v;
  __syncthreads();
  for (int off = 1; off < 256; off <<= 1) {
    int u = (j >= off) ? sm[t - off] : 0;
    __syncthreads();
    sm[t] += u;
    __syncthreads();
  }
  if (j < NBUK) bbase[r * NBUK + j] = sm[t] - v;
  if (j == 0) rp[r * (NN + 1) + NN] = EE;
}

// ---------------- phase 3: per-bucket CSR (deg, isd, rp, ci) all coalesced ----------------
__global__ __launch_bounds__(256) void k_csr(const uint2* __restrict__ bdata,
                                             const int* __restrict__ gcur,
                                             const int* __restrict__ bbase,
                                             float* __restrict__ isd,
                                             int* __restrict__ rp,
                                             int* __restrict__ ci) {
  __shared__ int lcnt[256];
  __shared__ int lrp[256];
  __shared__ int lcur[256];
  __shared__ int cstage[BCAP];
  const int b = blockIdx.x;
  const int r = blockIdx.y;
  const int t = threadIdx.x;
  const int cnt = gcur[r * NBUK + b];
  const int base = bbase[r * NBUK + b];
  const uint2* bd = bdata + (size_t)(r * NBUK + b) * BCAP;
  lcnt[t] = 0;
  lcur[t] = 0;
  __syncthreads();
  for (int s = t; s < cnt; s += 256) {
    uint2 pr = bd[s];
    atomicAdd(&lcnt[pr.y & 255], 1);
  }
  __syncthreads();
  int deg = lcnt[t];
  lrp[t] = deg;
  __syncthreads();
  for (int off = 1; off < 256; off <<= 1) {
    int u = (t >= off) ? lrp[t - off] : 0;
    __syncthreads();
    lrp[t] += u;
    __syncthreads();
  }
  int incl = lrp[t];
  __syncthreads();
  lrp[t] = incl - deg;  // exclusive
  __syncthreads();
  int node = b * 256 + t;
  if (node < NN) {
    isd[r * NN + node] = rsqrtf((float)(deg + 1));
    rp[r * (NN + 1) + node] = base + lrp[t];
  }
  for (int s = t; s < cnt; s += 256) {
    uint2 pr = bd[s];
    int j = (int)(pr.y & 255);
    int p = atomicAdd(&lcur[j], 1);
    cstage[lrp[j] + p] = (int)pr.x;
  }
  __syncthreads();
  for (int s = t; s < cnt; s += 256) ci[(size_t)r * EE + base + s] = cstage[s];
}

// ---------------- MFMA GEMM: xw[r][m][n] = X[m][:] @ W[r][:][n], bf16 out ----------------
#define AL_S 72    // 64+8 bf16 row stride
#define WT_S 136   // 128+8 bf16 row stride
template <int IN_BF16>
__global__ __launch_bounds__(256) void k_gemm(const void* __restrict__ Xv,
                                              const ushort* __restrict__ WTg,
                                              uint* __restrict__ Y) {
  __shared__ ushort WTl[128 * WT_S];
  __shared__ ushort Al[128 * AL_S];
  const int r = blockIdx.y;
  const int m0b = blockIdx.x * 128;
  const int t = threadIdx.x;
  const int w = t >> 6, L = t & 63, q = L >> 4, ln = L & 15;
  uint* Yr = Y + (size_t)r * NN * 64;
  const ushort* WTr = WTg + (size_t)r * 16384;

#pragma unroll
  for (int i = 0; i < 8; ++i) {
    int g = t + i * 256;
    int n = g >> 4, k0 = (g & 15) * 8;
    *(uint4*)(&WTl[n * WT_S + k0]) = *(const uint4*)(WTr + n * 128 + k0);
  }

  f32x4 acc[2][8];
#pragma unroll
  for (int mt = 0; mt < 2; ++mt)
#pragma unroll
    for (int nt = 0; nt < 8; ++nt) {
      acc[mt][nt][0] = 0.f; acc[mt][nt][1] = 0.f;
      acc[mt][nt][2] = 0.f; acc[mt][nt][3] = 0.f;
    }

  for (int hh = 0; hh < 2; ++hh) {
    __syncthreads();
    {
      int row = t >> 1, ch = t & 1;
      int gm = m0b + row;
      ushort* dst = &Al[row * AL_S + ch * 32];
      if (gm < NN) {
        if (IN_BF16) {
          const uint4* xp = (const uint4*)((const ushort*)Xv + (size_t)gm * 128 + hh * 64 + ch * 32);
#pragma unroll
          for (int j = 0; j < 4; ++j) ((uint4*)dst)[j] = xp[j];
        } else {
          const float4* xp = (const float4*)((const float*)Xv + (size_t)gm * 128 + hh * 64 + ch * 32);
          ushort tmp[32];
#pragma unroll
          for (int j = 0; j < 8; ++j) {
            float4 v = xp[j];
            tmp[j * 4 + 0] = f2b(v.x); tmp[j * 4 + 1] = f2b(v.y);
            tmp[j * 4 + 2] = f2b(v.z); tmp[j * 4 + 3] = f2b(v.w);
          }
#pragma unroll
          for (int j = 0; j < 4; ++j) ((uint4*)dst)[j] = ((uint4*)tmp)[j];
        }
      } else {
        uint4 z = make_uint4(0, 0, 0, 0);
#pragma unroll
        for (int j = 0; j < 4; ++j) ((uint4*)dst)[j] = z;
      }
    }
    __syncthreads();
#pragma unroll
    for (int kk = 0; kk < 2; ++kk) {
      bf16x8 b0 = *(const bf16x8*)(&Al[(w * 32 + ln) * AL_S + kk * 32 + q * 8]);
      bf16x8 b1 = *(const bf16x8*)(&Al[(w * 32 + 16 + ln) * AL_S + kk * 32 + q * 8]);
#pragma unroll
      for (int nt = 0; nt < 8; ++nt) {
        bf16x8 a = *(const bf16x8*)(&WTl[(nt * 16 + ln) * WT_S + hh * 64 + kk * 32 + q * 8]);
        acc[0][nt] = __builtin_amdgcn_mfma_f32_16x16x32_bf16(a, b0, acc[0][nt], 0, 0, 0);
        acc[1][nt] = __builtin_amdgcn_mfma_f32_16x16x32_bf16(a, b1, acc[1][nt], 0, 0, 0);
      }
    }
  }
#pragma unroll
  for (int mt = 0; mt < 2; ++mt) {
    int m = m0b + w * 32 + mt * 16 + ln;
    if (m < NN) {
      uint* yp = Yr + (size_t)m * 64 + q * 2;
#pragma unroll
      for (int nt = 0; nt < 8; ++nt) {
        f32x4 v = acc[mt][nt];
        uint lo = (uint)f2b(v[0]) | ((uint)f2b(v[1]) << 16);
        uint hi = (uint)f2b(v[2]) | ((uint)f2b(v[3]) << 16);
        *(uint2*)(yp + nt * 8) = make_uint2(lo, hi);
      }
    }
  }
}

// ---------------- aggregation: 1 wave per node, 2 channels/lane (packed bf16) ----------------
__global__ __launch_bounds__(256) void k_agg(const uint* __restrict__ xw,
                                             const int* __restrict__ rp,
                                             const int* __restrict__ ci,
                                             const float* __restrict__ isd,
                                             const float* __restrict__ bias,
                                             uint* __restrict__ hout, int relu_flag) {
  int w = threadIdx.x >> 6;
  int lane = threadIdx.x & 63;
  int i = blockIdx.x * 4 + w;
  float aLo = bias[lane * 2] + bias[DD + lane * 2];
  float aHi = bias[lane * 2 + 1] + bias[DD + lane * 2 + 1];
#pragma unroll
  for (int r = 0; r < RR; ++r) {
    const uint* xwr = xw + (size_t)r * NN * 64;
    const float* isdr = isd + r * NN;
    const int* cir = ci + (size_t)r * EE;
    float di = isdr[i];
    uint us = xwr[(size_t)i * 64 + lane];
    float dd = di * di;
    aLo += blo(us) * dd;
    aHi += bhi(us) * dd;
    int e0 = rp[r * (NN + 1) + i];
    int e1 = rp[r * (NN + 1) + i + 1];
    int e = e0;
    for (; e + 8 <= e1; e += 8) {
      int s[8];
      uint u[8];
      float wt[8];
#pragma unroll
      for (int j = 0; j < 8; ++j) s[j] = cir[e + j];
#pragma unroll
      for (int j = 0; j < 8; ++j) u[j] = xwr[(size_t)s[j] * 64 + lane];
#pragma unroll
      for (int j = 0; j < 8; ++j) wt[j] = isdr[s[j]] * di;
#pragma unroll
      for (int j = 0; j < 8; ++j) {
        aLo += blo(u[j]) * wt[j];
        aHi += bhi(u[j]) * wt[j];
      }
    }
    for (; e < e1; ++e) {
      int s = cir[e];
      float wt = isdr[s] * di;
      uint u = xwr[(size_t)s * 64 + lane];
      aLo += blo(u) * wt;
      aHi += bhi(u) * wt;
    }
  }
  if (relu_flag) {
    aLo = fmaxf(aLo, 0.f);
    aHi = fmaxf(aHi, 0.f);
  }
  hout[(size_t)i * 64 + lane] = (uint)f2b(aLo) | ((uint)f2b(aHi) << 16);
}

// ---------------- pooling (batch ids sorted), packed bf16 input ----------------
__global__ __launch_bounds__(64) void k_pool(const uint* __restrict__ h,
                                             const int* __restrict__ batch,
                                             float* __restrict__ sums,
                                             int* __restrict__ counts) {
  int lane = threadIdx.x;
  int n0 = blockIdx.x * 256;
  int n1 = n0 + 256;
  if (n1 > NN) n1 = NN;
  if (n0 >= NN) return;
  float aLo = 0.f, aHi = 0.f;
  int cnt = 0;
  int g = batch[n0];
  for (int n = n0; n < n1; ++n) {
    int gn = batch[n];
    if (gn != g) {
      atomicAdd(&sums[g * DD + lane * 2], aLo);
      atomicAdd(&sums[g * DD + lane * 2 + 1], aHi);
      if (lane == 0) atomicAdd(&counts[g], cnt);
      aLo = 0.f; aHi = 0.f; cnt = 0;
      g = gn;
    }
    uint u = h[(size_t)n * 64 + lane];
    aLo += blo(u);
    aHi += bhi(u);
    cnt++;
  }
  atomicAdd(&sums[g * DD + lane * 2], aLo);
  atomicAdd(&sums[g * DD + lane * 2 + 1], aHi);
  if (lane == 0) atomicAdd(&counts[g], cnt);
}

__global__ __launch_bounds__(512) void k_final(const float* __restrict__ sums,
                                               const int* __restrict__ counts,
                                               const float* __restrict__ lin_w,
                                               const float* __restrict__ lin_b,
                                               float* __restrict__ out) {
  int t = threadIdx.x;  // 512 = 64 graphs x 8 classes
  int g = t >> 3, co = t & 7;
  float cnt = (float)counts[g];
  if (cnt < 1.f) cnt = 1.f;
  float inv = 1.f / cnt;
  float v = lin_b[co];
  for (int d = 0; d < DD; ++d) v += (sums[g * DD + d] * inv) * lin_w[d * CCLS + co];
  out[t] = v;
}

extern "C" void kernel_launch(void* const* d_in, const int* in_sizes, int n_in,
                              void* d_out, int out_size, void* d_ws, size_t ws_size,
                              hipStream_t stream) {
  (void)in_sizes; (void)n_in; (void)out_size; (void)ws_size;
  const float* x     = (const float*)d_in[0];
  const float* W     = (const float*)d_in[1];
  const float* b     = (const float*)d_in[2];
  const float* lin_w = (const float*)d_in[3];
  const float* lin_b = (const float*)d_in[4];
  const int*   EI    = (const int*)d_in[5];
  const int*   batch = (const int*)d_in[6];
  float* out = (float*)d_out;

  char* ws = (char*)d_ws;
  uint*   xw    = (uint*)(ws + OFF_XW);
  uint*   h1    = (uint*)(ws + OFF_H1);
  ushort* WbfT  = (ushort*)(ws + OFF_WBT);
  float*  isd   = (float*)(ws + OFF_ISD);
  int*    rp    = (int*)(ws + OFF_RP);
  int*    ci    = (int*)(ws + OFF_CI);
  uint2*  bdata = (uint2*)(ws + OFF_BD);
  int*    bbase = (int*)(ws + OFF_BB);
  char*   zb    = ws + OFF_ZERO;
  int*    gcur  = (int*)(zb + ZO_GCUR);
  float*  sums  = (float*)(zb + ZO_SUM);
  int*    counts= (int*)(zb + ZO_CNT);

  (void)hipMemsetAsync(zb, 0, ZERO_BYTES, stream);

  k_wprep<<<256, 256, 0, stream>>>(W, WbfT);
  k_part<<<dim3((EE + 4095) / 4096, RR), 256, 0, stream>>>(EI, gcur, bdata);
  k_bscan<<<1, 512, 0, stream>>>(gcur, bbase, rp);
  k_csr<<<dim3(NBUK, RR), 256, 0, stream>>>(bdata, gcur, bbase, isd, rp, ci);

  for (int l = 0; l < LL; ++l) {
    const ushort* WTl_g = WbfT + (size_t)l * RR * DD * DD;
    if (l == 0)
      k_gemm<0><<<dim3((NN + 127) / 128, RR), 256, 0, stream>>>((const void*)x, WTl_g, xw);
    else
      k_gemm<1><<<dim3((NN + 127) / 128, RR), 256, 0, stream>>>((const void*)h1, WTl_g, xw);
    k_agg<<<(NN + 3) / 4, 256, 0, stream>>>(xw, rp, ci, isd, b + (size_t)l * RR * DD, h1,
                                            (l < LL - 1) ? 1 : 0);
  }
  k_pool<<<(NN + 255) / 256, 64, 0, stream>>>(h1, batch, sums, counts);
  k_final<<<1, GG * CCLS, 0, stream>>>(sums, counts, lin_w, lin_b, out);
}

// Round 4
// 354.562 us; speedup vs baseline: 1.8819x; 1.0447x over previous
//
#include <hip/hip_runtime.h>
#include <math.h>

#define NN 50000
#define EE 800000
#define RR 2
#define LL 2
#define DD 128
#define GG 64
#define CCLS 8
#define NBUK 196     // buckets of 256 dst nodes: bucket = dst >> 8
#define BCAP 6144    // max edges per bucket (mean 4082, sigma 64)

typedef unsigned int uint;
typedef unsigned short ushort;
typedef short bf16x8 __attribute__((ext_vector_type(8)));
typedef float f32x4 __attribute__((ext_vector_type(4)));
typedef float f32x2 __attribute__((ext_vector_type(2)));

// ---------------- workspace layout (bytes) ----------------
#define OFF_XW    ((size_t)0)           // [2][N][128] fp8 e4m3            12,800,000
#define OFF_H1    ((size_t)12800000)    // [N][64] uint (packed bf16)      12,800,000
#define OFF_WBT   ((size_t)25600000)    // [L][R][128][128] bf16              131,072
#define OFF_ISD   ((size_t)25731072)    // [2][N] f32                         400,000
#define OFF_RP    ((size_t)26131072)    // [2][N+1] i32                       400,064
#define OFF_CI    ((size_t)26531136)    // [2][E] i32                       6,400,000
#define OFF_BD    ((size_t)32931136)    // [2][196][6144] uint              9,633,792
#define OFF_ZERO  ((size_t)42564928)
// zero region internal offsets (bytes)
#define ZO_GCUR 0        // [2][196] i32 bucket counters (1568 B, pad 1600)
#define ZO_SUM  1600     // [G][D] f32 (32768 B)
#define ZO_CNT  34368    // [G] i32 (256 B)
#define ZERO_BYTES 34624

static __device__ __forceinline__ ushort f2b(float f) {
  uint u = __float_as_uint(f);
  uint r = (u + 0x7fffu + ((u >> 16) & 1u)) >> 16;
  return (ushort)r;
}
static __device__ __forceinline__ float blo(uint u) { return __uint_as_float(u << 16); }
static __device__ __forceinline__ float bhi(uint u) { return __uint_as_float(u & 0xffff0000u); }

// ---------------- W prep: fp32 W[l][r][k][n] -> bf16 WbfT[l][r][n][k] ----------------
__global__ __launch_bounds__(256) void k_wprep(const float* __restrict__ W,
                                               ushort* __restrict__ WT) {
  int idx = blockIdx.x * 256 + threadIdx.x;  // 65536 total
  int lr = idx >> 14;
  int rem = idx & 16383;
  int n = rem >> 7, k = rem & 127;
  WT[lr * 16384 + n * 128 + k] = f2b(W[lr * 16384 + k * 128 + n]);
}

// ---------------- phase 1: partition edges into dst buckets (coalesced) ----------------
__global__ __launch_bounds__(256) void k_part(const int* __restrict__ EI,
                                              int* __restrict__ gcur,
                                              uint* __restrict__ bdata) {
  __shared__ int hist[256];   // bucket counts -> stage-exclusive offsets
  __shared__ int sbase[256];  // scan scratch
  __shared__ int gbase[256];  // global reservation base per bucket
  __shared__ int lcur[256];
  __shared__ uint stage[4096];
  __shared__ unsigned char bstage[4096];
  const int r = blockIdx.y;
  const int t = threadIdx.x;
  const int e0 = blockIdx.x * 4096;
  const int cnt = min(4096, EE - e0);
  hist[t] = 0;
  lcur[t] = 0;
  __syncthreads();

  int src[16], dst[16];
  bool val[4];
#pragma unroll
  for (int j = 0; j < 4; ++j) {
    int i4 = (j * 256 + t) * 4;
    val[j] = (i4 < cnt);
    if (val[j]) {
      int4 s4 = *(const int4*)(EI + (size_t)r * 2 * EE + e0 + i4);
      int4 d4 = *(const int4*)(EI + (size_t)r * 2 * EE + EE + e0 + i4);
      src[j * 4 + 0] = s4.x; src[j * 4 + 1] = s4.y; src[j * 4 + 2] = s4.z; src[j * 4 + 3] = s4.w;
      dst[j * 4 + 0] = d4.x; dst[j * 4 + 1] = d4.y; dst[j * 4 + 2] = d4.z; dst[j * 4 + 3] = d4.w;
#pragma unroll
      for (int i = 0; i < 4; ++i) atomicAdd(&hist[dst[j * 4 + i] >> 8], 1);
    }
  }
  __syncthreads();
  int hv = hist[t];
  if (t < NBUK && hv > 0)
    gbase[t] = atomicAdd(&gcur[r * NBUK + t], hv);
  else
    gbase[t] = 0;
  sbase[t] = hv;
  __syncthreads();
  for (int off = 1; off < 256; off <<= 1) {
    int u = (t >= off) ? sbase[t - off] : 0;
    __syncthreads();
    sbase[t] += u;
    __syncthreads();
  }
  int incl = sbase[t];
  hist[t] = incl - hv;  // exclusive stage offset
  __syncthreads();
#pragma unroll
  for (int j = 0; j < 4; ++j) {
    if (val[j]) {
#pragma unroll
      for (int i = 0; i < 4; ++i) {
        int d = dst[j * 4 + i];
        int b = d >> 8;
        int p = atomicAdd(&lcur[b], 1);
        int pos = hist[b] + p;
        stage[pos] = ((uint)src[j * 4 + i] << 8) | (uint)(d & 255);
        bstage[pos] = (unsigned char)b;
      }
    }
  }
  __syncthreads();
  for (int s = t; s < cnt; s += 256) {
    int b = (int)bstage[s];
    bdata[(size_t)(r * NBUK + b) * BCAP + gbase[b] + (s - hist[b])] = stage[s];
  }
}

// ---------------- phase 2: per-bucket CSR (deg, isd, rp, ci) all coalesced ----------------
__global__ __launch_bounds__(256) void k_csr(const uint* __restrict__ bdata,
                                             const int* __restrict__ gcur,
                                             float* __restrict__ isd,
                                             int* __restrict__ rp,
                                             int* __restrict__ ci) {
  __shared__ int lcnt[256];
  __shared__ int lrp[256];
  __shared__ int lcur[256];
  __shared__ int cstage[BCAP];
  __shared__ int basesh;
  const int b = blockIdx.x;
  const int r = blockIdx.y;
  const int t = threadIdx.x;
  const int cnt = gcur[r * NBUK + b];
  // bucket base = prefix sum of gcur[r][0..b-1] (NBUK <= 256: 1 elem/thread)
  lcnt[t] = (t < b) ? gcur[r * NBUK + t] : 0;
  __syncthreads();
  for (int off = 128; off > 0; off >>= 1) {
    if (t < off) lcnt[t] += lcnt[t + off];
    __syncthreads();
  }
  if (t == 0) basesh = lcnt[0];
  __syncthreads();
  const int base = basesh;
  const uint* bd = bdata + (size_t)(r * NBUK + b) * BCAP;
  __syncthreads();
  lcnt[t] = 0;
  lcur[t] = 0;
  __syncthreads();
  for (int s = t; s < cnt; s += 256) {
    uint pr = bd[s];
    atomicAdd(&lcnt[pr & 255u], 1);
  }
  __syncthreads();
  int deg = lcnt[t];
  lrp[t] = deg;
  __syncthreads();
  for (int off = 1; off < 256; off <<= 1) {
    int u = (t >= off) ? lrp[t - off] : 0;
    __syncthreads();
    lrp[t] += u;
    __syncthreads();
  }
  int incl = lrp[t];
  __syncthreads();
  lrp[t] = incl - deg;  // exclusive
  __syncthreads();
  int node = b * 256 + t;
  if (node < NN) {
    isd[r * NN + node] = rsqrtf((float)(deg + 1));
    rp[r * (NN + 1) + node] = base + lrp[t];
  }
  if (b == NBUK - 1 && t == 0) rp[r * (NN + 1) + NN] = EE;
  for (int s = t; s < cnt; s += 256) {
    uint pr = bd[s];
    int j = (int)(pr & 255u);
    int p = atomicAdd(&lcur[j], 1);
    cstage[lrp[j] + p] = (int)(pr >> 8);
  }
  __syncthreads();
  for (int s = t; s < cnt; s += 256) ci[(size_t)r * EE + base + s] = cstage[s];
}

// ---------------- MFMA GEMM: xw[r][m][n] = X[m][:] @ W[r][:][n], fp8 out ----------------
#define AL_S 72    // 64+8 bf16 row stride
#define WT_S 136   // 128+8 bf16 row stride
template <int IN_BF16>
__global__ __launch_bounds__(256) void k_gemm(const void* __restrict__ Xv,
                                              const ushort* __restrict__ WTg,
                                              uint* __restrict__ Y) {
  __shared__ ushort WTl[128 * WT_S];
  __shared__ ushort Al[128 * AL_S];
  const int r = blockIdx.y;
  const int m0b = blockIdx.x * 128;
  const int t = threadIdx.x;
  const int w = t >> 6, L = t & 63, q = L >> 4, ln = L & 15;
  uint* Yr = Y + (size_t)r * NN * 32;   // fp8 row = 32 uints
  const ushort* WTr = WTg + (size_t)r * 16384;

#pragma unroll
  for (int i = 0; i < 8; ++i) {
    int g = t + i * 256;
    int n = g >> 4, k0 = (g & 15) * 8;
    *(uint4*)(&WTl[n * WT_S + k0]) = *(const uint4*)(WTr + n * 128 + k0);
  }

  f32x4 acc[2][8];
#pragma unroll
  for (int mt = 0; mt < 2; ++mt)
#pragma unroll
    for (int nt = 0; nt < 8; ++nt) {
      acc[mt][nt][0] = 0.f; acc[mt][nt][1] = 0.f;
      acc[mt][nt][2] = 0.f; acc[mt][nt][3] = 0.f;
    }

  for (int hh = 0; hh < 2; ++hh) {
    __syncthreads();
    {
      int row = t >> 1, ch = t & 1;
      int gm = m0b + row;
      ushort* dst = &Al[row * AL_S + ch * 32];
      if (gm < NN) {
        if (IN_BF16) {
          const uint4* xp = (const uint4*)((const ushort*)Xv + (size_t)gm * 128 + hh * 64 + ch * 32);
#pragma unroll
          for (int j = 0; j < 4; ++j) ((uint4*)dst)[j] = xp[j];
        } else {
          const float4* xp = (const float4*)((const float*)Xv + (size_t)gm * 128 + hh * 64 + ch * 32);
          ushort tmp[32];
#pragma unroll
          for (int j = 0; j < 8; ++j) {
            float4 v = xp[j];
            tmp[j * 4 + 0] = f2b(v.x); tmp[j * 4 + 1] = f2b(v.y);
            tmp[j * 4 + 2] = f2b(v.z); tmp[j * 4 + 3] = f2b(v.w);
          }
#pragma unroll
          for (int j = 0; j < 4; ++j) ((uint4*)dst)[j] = ((uint4*)tmp)[j];
        }
      } else {
        uint4 z = make_uint4(0, 0, 0, 0);
#pragma unroll
        for (int j = 0; j < 4; ++j) ((uint4*)dst)[j] = z;
      }
    }
    __syncthreads();
#pragma unroll
    for (int kk = 0; kk < 2; ++kk) {
      bf16x8 b0 = *(const bf16x8*)(&Al[(w * 32 + ln) * AL_S + kk * 32 + q * 8]);
      bf16x8 b1 = *(const bf16x8*)(&Al[(w * 32 + 16 + ln) * AL_S + kk * 32 + q * 8]);
#pragma unroll
      for (int nt = 0; nt < 8; ++nt) {
        bf16x8 a = *(const bf16x8*)(&WTl[(nt * 16 + ln) * WT_S + hh * 64 + kk * 32 + q * 8]);
        acc[0][nt] = __builtin_amdgcn_mfma_f32_16x16x32_bf16(a, b0, acc[0][nt], 0, 0, 0);
        acc[1][nt] = __builtin_amdgcn_mfma_f32_16x16x32_bf16(a, b1, acc[1][nt], 0, 0, 0);
      }
    }
  }
  // epilogue: lane holds D for m = m0b + w*32 + mt*16 + ln, n = nt*16 + q*4 + reg
  // fp8 pack: 4 consecutive channels -> 1 uint at uint-index nt*4 + q
#pragma unroll
  for (int mt = 0; mt < 2; ++mt) {
    int m = m0b + w * 32 + mt * 16 + ln;
    if (m < NN) {
      uint* yp = Yr + (size_t)m * 32;
#pragma unroll
      for (int nt = 0; nt < 8; ++nt) {
        f32x4 v = acc[mt][nt];
        uint u = __builtin_amdgcn_cvt_pk_fp8_f32(v[0], v[1], 0u, false);
        u = __builtin_amdgcn_cvt_pk_fp8_f32(v[2], v[3], u, true);
        yp[nt * 4 + q] = u;
      }
    }
  }
}

// ---------------- aggregation: 1 wave per node, 2 channels/lane (fp8 gather) ----------------
__global__ __launch_bounds__(256) void k_agg(const ushort* __restrict__ xw,
                                             const int* __restrict__ rp,
                                             const int* __restrict__ ci,
                                             const float* __restrict__ isd,
                                             const float* __restrict__ bias,
                                             uint* __restrict__ hout, int relu_flag) {
  int w = threadIdx.x >> 6;
  int lane = threadIdx.x & 63;
  int i = blockIdx.x * 4 + w;
  float aLo = bias[lane * 2] + bias[DD + lane * 2];
  float aHi = bias[lane * 2 + 1] + bias[DD + lane * 2 + 1];
#pragma unroll
  for (int r = 0; r < RR; ++r) {
    const ushort* xwr = xw + (size_t)r * NN * 64;  // fp8 row = 64 ushorts
    const float* isdr = isd + r * NN;
    const int* cir = ci + (size_t)r * EE;
    float di = isdr[i];
    {
      f32x2 v = __builtin_amdgcn_cvt_pk_f32_fp8((uint)xwr[(size_t)i * 64 + lane], false);
      float dd = di * di;
      aLo += v[0] * dd;
      aHi += v[1] * dd;
    }
    int e0 = rp[r * (NN + 1) + i];
    int e1 = rp[r * (NN + 1) + i + 1];
    int e = e0;
    for (; e + 8 <= e1; e += 8) {
      int s[8];
      uint u[8];
      float wt[8];
#pragma unroll
      for (int j = 0; j < 8; ++j) s[j] = cir[e + j];
#pragma unroll
      for (int j = 0; j < 8; ++j) u[j] = (uint)xwr[(size_t)s[j] * 64 + lane];
#pragma unroll
      for (int j = 0; j < 8; ++j) wt[j] = isdr[s[j]] * di;
#pragma unroll
      for (int j = 0; j < 8; ++j) {
        f32x2 v = __builtin_amdgcn_cvt_pk_f32_fp8(u[j], false);
        aLo += v[0] * wt[j];
        aHi += v[1] * wt[j];
      }
    }
    for (; e < e1; ++e) {
      int s = cir[e];
      float wt = isdr[s] * di;
      f32x2 v = __builtin_amdgcn_cvt_pk_f32_fp8((uint)xwr[(size_t)s * 64 + lane], false);
      aLo += v[0] * wt;
      aHi += v[1] * wt;
    }
  }
  if (relu_flag) {
    aLo = fmaxf(aLo, 0.f);
    aHi = fmaxf(aHi, 0.f);
  }
  hout[(size_t)i * 64 + lane] = (uint)f2b(aLo) | ((uint)f2b(aHi) << 16);
}

// ---------------- pooling (batch ids sorted), packed bf16 input ----------------
__global__ __launch_bounds__(64) void k_pool(const uint* __restrict__ h,
                                             const int* __restrict__ batch,
                                             float* __restrict__ sums,
                                             int* __restrict__ counts) {
  int lane = threadIdx.x;
  int n0 = blockIdx.x * 256;
  int n1 = n0 + 256;
  if (n1 > NN) n1 = NN;
  if (n0 >= NN) return;
  float aLo = 0.f, aHi = 0.f;
  int cnt = 0;
  int g = batch[n0];
  for (int n = n0; n < n1; ++n) {
    int gn = batch[n];
    if (gn != g) {
      atomicAdd(&sums[g * DD + lane * 2], aLo);
      atomicAdd(&sums[g * DD + lane * 2 + 1], aHi);
      if (lane == 0) atomicAdd(&counts[g], cnt);
      aLo = 0.f; aHi = 0.f; cnt = 0;
      g = gn;
    }
    uint u = h[(size_t)n * 64 + lane];
    aLo += blo(u);
    aHi += bhi(u);
    cnt++;
  }
  atomicAdd(&sums[g * DD + lane * 2], aLo);
  atomicAdd(&sums[g * DD + lane * 2 + 1], aHi);
  if (lane == 0) atomicAdd(&counts[g], cnt);
}

__global__ __launch_bounds__(512) void k_final(const float* __restrict__ sums,
                                               const int* __restrict__ counts,
                                               const float* __restrict__ lin_w,
                                               const float* __restrict__ lin_b,
                                               float* __restrict__ out) {
  int t = threadIdx.x;  // 512 = 64 graphs x 8 classes
  int g = t >> 3, co = t & 7;
  float cnt = (float)counts[g];
  if (cnt < 1.f) cnt = 1.f;
  float inv = 1.f / cnt;
  float v = lin_b[co];
  for (int d = 0; d < DD; ++d) v += (sums[g * DD + d] * inv) * lin_w[d * CCLS + co];
  out[t] = v;
}

extern "C" void kernel_launch(void* const* d_in, const int* in_sizes, int n_in,
                              void* d_out, int out_size, void* d_ws, size_t ws_size,
                              hipStream_t stream) {
  (void)in_sizes; (void)n_in; (void)out_size; (void)ws_size;
  const float* x     = (const float*)d_in[0];
  const float* W     = (const float*)d_in[1];
  const float* b     = (const float*)d_in[2];
  const float* lin_w = (const float*)d_in[3];
  const float* lin_b = (const float*)d_in[4];
  const int*   EI    = (const int*)d_in[5];
  const int*   batch = (const int*)d_in[6];
  float* out = (float*)d_out;

  char* ws = (char*)d_ws;
  uint*   xw    = (uint*)(ws + OFF_XW);       // fp8 table
  uint*   h1    = (uint*)(ws + OFF_H1);       // bf16 packed
  ushort* WbfT  = (ushort*)(ws + OFF_WBT);
  float*  isd   = (float*)(ws + OFF_ISD);
  int*    rp    = (int*)(ws + OFF_RP);
  int*    ci    = (int*)(ws + OFF_CI);
  uint*   bdata = (uint*)(ws + OFF_BD);
  char*   zb    = ws + OFF_ZERO;
  int*    gcur  = (int*)(zb + ZO_GCUR);
  float*  sums  = (float*)(zb + ZO_SUM);
  int*    counts= (int*)(zb + ZO_CNT);

  (void)hipMemsetAsync(zb, 0, ZERO_BYTES, stream);

  k_wprep<<<256, 256, 0, stream>>>(W, WbfT);
  k_part<<<dim3((EE + 4095) / 4096, RR), 256, 0, stream>>>(EI, gcur, bdata);
  k_csr<<<dim3(NBUK, RR), 256, 0, stream>>>(bdata, gcur, isd, rp, ci);

  for (int l = 0; l < LL; ++l) {
    const ushort* WTl_g = WbfT + (size_t)l * RR * DD * DD;
    if (l == 0)
      k_gemm<0><<<dim3((NN + 127) / 128, RR), 256, 0, stream>>>((const void*)x, WTl_g, xw);
    else
      k_gemm<1><<<dim3((NN + 127) / 128, RR), 256, 0, stream>>>((const void*)h1, WTl_g, xw);
    k_agg<<<(NN + 3) / 4, 256, 0, stream>>>((const ushort*)xw, rp, ci, isd,
                                            b + (size_t)l * RR * DD, h1,
                                            (l < LL - 1) ? 1 : 0);
  }
  k_pool<<<(NN + 255) / 256, 64, 0, stream>>>(h1, batch, sums, counts);
  k_final<<<1, GG * CCLS, 0, stream>>>(sums, counts, lin_w, lin_b, out);
}

// Round 5
// 297.722 us; speedup vs baseline: 2.2411x; 1.1909x over previous
//
#include <hip/hip_runtime.h>
#include <math.h>

#define NN 50000
#define EE 800000
#define RR 2
#define LL 2
#define DD 128
#define GG 64
#define CCLS 8
#define NBUK 196     // buckets of 256 dst nodes: bucket = dst >> 8
#define BCAP 6144    // max edges per bucket (mean 4082, sigma 64)

typedef unsigned int uint;
typedef unsigned short ushort;
typedef short bf16x8 __attribute__((ext_vector_type(8)));
typedef float f32x4 __attribute__((ext_vector_type(4)));
typedef float f32x2 __attribute__((ext_vector_type(2)));

// ---------------- workspace layout (bytes) ----------------
#define OFF_XW    ((size_t)0)           // [2][N][128] fp8 e4m3            12,800,000
#define OFF_H1    ((size_t)12800000)    // [N][64] uint (packed bf16)      12,800,000
#define OFF_WBT   ((size_t)25600000)    // [L][R][128][128] bf16              131,072
#define OFF_ISD   ((size_t)25731072)    // [2][N] f32                         400,000
#define OFF_RP    ((size_t)26131072)    // [2][N+1] i32                       400,064
#define OFF_CI    ((size_t)26531136)    // [2][E] i32                       6,400,000
#define OFF_BD    ((size_t)32931136)    // [2][196][6144] uint              9,633,792
#define OFF_ZERO  ((size_t)42564928)
// zero region internal offsets (bytes)
#define ZO_GCUR 0        // [2][196] i32 bucket counters (1568 B, pad 1600)
#define ZO_SUM  1600     // [G][D] f32 (32768 B)
#define ZO_CNT  34368    // [G] i32 (256 B)
#define ZERO_BYTES 34624

static __device__ __forceinline__ ushort f2b(float f) {
  uint u = __float_as_uint(f);
  uint r = (u + 0x7fffu + ((u >> 16) & 1u)) >> 16;
  return (ushort)r;
}
static __device__ __forceinline__ float blo(uint u) { return __uint_as_float(u << 16); }
static __device__ __forceinline__ float bhi(uint u) { return __uint_as_float(u & 0xffff0000u); }

// ---------------- W prep: fp32 W[l][r][k][n] -> bf16 WbfT[l][r][n][k] ----------------
__global__ __launch_bounds__(256) void k_wprep(const float* __restrict__ W,
                                               ushort* __restrict__ WT) {
  int idx = blockIdx.x * 256 + threadIdx.x;  // 65536 total
  int lr = idx >> 14;
  int rem = idx & 16383;
  int n = rem >> 7, k = rem & 127;
  WT[lr * 16384 + n * 128 + k] = f2b(W[lr * 16384 + k * 128 + n]);
}

// ---------------- phase 1: partition edges into dst buckets (coalesced) ----------------
__global__ __launch_bounds__(256) void k_part(const int* __restrict__ EI,
                                              int* __restrict__ gcur,
                                              uint* __restrict__ bdata) {
  __shared__ int hist[256];   // bucket counts -> stage-exclusive offsets
  __shared__ int sbase[256];  // scan scratch
  __shared__ int gbase[256];  // global reservation base per bucket
  __shared__ int lcur[256];
  __shared__ uint stage[4096];
  __shared__ unsigned char bstage[4096];
  const int r = blockIdx.y;
  const int t = threadIdx.x;
  const int e0 = blockIdx.x * 4096;
  const int cnt = min(4096, EE - e0);
  hist[t] = 0;
  lcur[t] = 0;
  __syncthreads();

  int src[16], dst[16];
  bool val[4];
#pragma unroll
  for (int j = 0; j < 4; ++j) {
    int i4 = (j * 256 + t) * 4;
    val[j] = (i4 < cnt);
    if (val[j]) {
      int4 s4 = *(const int4*)(EI + (size_t)r * 2 * EE + e0 + i4);
      int4 d4 = *(const int4*)(EI + (size_t)r * 2 * EE + EE + e0 + i4);
      src[j * 4 + 0] = s4.x; src[j * 4 + 1] = s4.y; src[j * 4 + 2] = s4.z; src[j * 4 + 3] = s4.w;
      dst[j * 4 + 0] = d4.x; dst[j * 4 + 1] = d4.y; dst[j * 4 + 2] = d4.z; dst[j * 4 + 3] = d4.w;
#pragma unroll
      for (int i = 0; i < 4; ++i) atomicAdd(&hist[dst[j * 4 + i] >> 8], 1);
    }
  }
  __syncthreads();
  int hv = hist[t];
  if (t < NBUK && hv > 0)
    gbase[t] = atomicAdd(&gcur[r * NBUK + t], hv);
  else
    gbase[t] = 0;
  sbase[t] = hv;
  __syncthreads();
  for (int off = 1; off < 256; off <<= 1) {
    int u = (t >= off) ? sbase[t - off] : 0;
    __syncthreads();
    sbase[t] += u;
    __syncthreads();
  }
  int incl = sbase[t];
  hist[t] = incl - hv;  // exclusive stage offset
  __syncthreads();
#pragma unroll
  for (int j = 0; j < 4; ++j) {
    if (val[j]) {
#pragma unroll
      for (int i = 0; i < 4; ++i) {
        int d = dst[j * 4 + i];
        int b = d >> 8;
        int p = atomicAdd(&lcur[b], 1);
        int pos = hist[b] + p;
        stage[pos] = ((uint)src[j * 4 + i] << 8) | (uint)(d & 255);
        bstage[pos] = (unsigned char)b;
      }
    }
  }
  __syncthreads();
  for (int s = t; s < cnt; s += 256) {
    int b = (int)bstage[s];
    bdata[(size_t)(r * NBUK + b) * BCAP + gbase[b] + (s - hist[b])] = stage[s];
  }
}

// ---------------- phase 2: per-bucket CSR (deg, isd, rp, ci) all coalesced ----------------
__global__ __launch_bounds__(256) void k_csr(const uint* __restrict__ bdata,
                                             const int* __restrict__ gcur,
                                             float* __restrict__ isd,
                                             int* __restrict__ rp,
                                             int* __restrict__ ci) {
  __shared__ int lcnt[256];
  __shared__ int lrp[256];
  __shared__ int lcur[256];
  __shared__ int cstage[BCAP];
  __shared__ int basesh;
  const int b = blockIdx.x;
  const int r = blockIdx.y;
  const int t = threadIdx.x;
  const int cnt = gcur[r * NBUK + b];
  // bucket base = prefix sum of gcur[r][0..b-1] (NBUK <= 256: 1 elem/thread)
  lcnt[t] = (t < b) ? gcur[r * NBUK + t] : 0;
  __syncthreads();
  for (int off = 128; off > 0; off >>= 1) {
    if (t < off) lcnt[t] += lcnt[t + off];
    __syncthreads();
  }
  if (t == 0) basesh = lcnt[0];
  __syncthreads();
  const int base = basesh;
  const uint* bd = bdata + (size_t)(r * NBUK + b) * BCAP;
  __syncthreads();
  lcnt[t] = 0;
  lcur[t] = 0;
  __syncthreads();
  for (int s = t; s < cnt; s += 256) {
    uint pr = bd[s];
    atomicAdd(&lcnt[pr & 255u], 1);
  }
  __syncthreads();
  int deg = lcnt[t];
  lrp[t] = deg;
  __syncthreads();
  for (int off = 1; off < 256; off <<= 1) {
    int u = (t >= off) ? lrp[t - off] : 0;
    __syncthreads();
    lrp[t] += u;
    __syncthreads();
  }
  int incl = lrp[t];
  __syncthreads();
  lrp[t] = incl - deg;  // exclusive
  __syncthreads();
  int node = b * 256 + t;
  if (node < NN) {
    isd[r * NN + node] = rsqrtf((float)(deg + 1));
    rp[r * (NN + 1) + node] = base + lrp[t];
  }
  if (b == NBUK - 1 && t == 0) rp[r * (NN + 1) + NN] = EE;
  for (int s = t; s < cnt; s += 256) {
    uint pr = bd[s];
    int j = (int)(pr & 255u);
    int p = atomicAdd(&lcur[j], 1);
    cstage[lrp[j] + p] = (int)(pr >> 8);
  }
  __syncthreads();
  for (int s = t; s < cnt; s += 256) ci[(size_t)r * EE + base + s] = cstage[s];
}

// ---------------- MFMA GEMM: xw[r][m][n] = X[m][:] @ W[r][:][n], fp8 out ----------------
#define AL_S 72    // 64+8 bf16 row stride
#define WT_S 136   // 128+8 bf16 row stride
template <int IN_BF16>
__global__ __launch_bounds__(256) void k_gemm(const void* __restrict__ Xv,
                                              const ushort* __restrict__ WTg,
                                              uint* __restrict__ Y) {
  __shared__ ushort WTl[128 * WT_S];
  __shared__ ushort Al[128 * AL_S];
  const int r = blockIdx.y;
  const int m0b = blockIdx.x * 128;
  const int t = threadIdx.x;
  const int w = t >> 6, L = t & 63, q = L >> 4, ln = L & 15;
  uint* Yr = Y + (size_t)r * NN * 32;   // fp8 row = 32 uints
  const ushort* WTr = WTg + (size_t)r * 16384;

#pragma unroll
  for (int i = 0; i < 8; ++i) {
    int g = t + i * 256;
    int n = g >> 4, k0 = (g & 15) * 8;
    *(uint4*)(&WTl[n * WT_S + k0]) = *(const uint4*)(WTr + n * 128 + k0);
  }

  f32x4 acc[2][8];
#pragma unroll
  for (int mt = 0; mt < 2; ++mt)
#pragma unroll
    for (int nt = 0; nt < 8; ++nt) {
      acc[mt][nt][0] = 0.f; acc[mt][nt][1] = 0.f;
      acc[mt][nt][2] = 0.f; acc[mt][nt][3] = 0.f;
    }

  for (int hh = 0; hh < 2; ++hh) {
    __syncthreads();
    {
      int row = t >> 1, ch = t & 1;
      int gm = m0b + row;
      ushort* dst = &Al[row * AL_S + ch * 32];
      if (gm < NN) {
        if (IN_BF16) {
          const uint4* xp = (const uint4*)((const ushort*)Xv + (size_t)gm * 128 + hh * 64 + ch * 32);
#pragma unroll
          for (int j = 0; j < 4; ++j) ((uint4*)dst)[j] = xp[j];
        } else {
          const float4* xp = (const float4*)((const float*)Xv + (size_t)gm * 128 + hh * 64 + ch * 32);
          ushort tmp[32];
#pragma unroll
          for (int j = 0; j < 8; ++j) {
            float4 v = xp[j];
            tmp[j * 4 + 0] = f2b(v.x); tmp[j * 4 + 1] = f2b(v.y);
            tmp[j * 4 + 2] = f2b(v.z); tmp[j * 4 + 3] = f2b(v.w);
          }
#pragma unroll
          for (int j = 0; j < 4; ++j) ((uint4*)dst)[j] = ((uint4*)tmp)[j];
        }
      } else {
        uint4 z = make_uint4(0, 0, 0, 0);
#pragma unroll
        for (int j = 0; j < 4; ++j) ((uint4*)dst)[j] = z;
      }
    }
    __syncthreads();
#pragma unroll
    for (int kk = 0; kk < 2; ++kk) {
      bf16x8 b0 = *(const bf16x8*)(&Al[(w * 32 + ln) * AL_S + kk * 32 + q * 8]);
      bf16x8 b1 = *(const bf16x8*)(&Al[(w * 32 + 16 + ln) * AL_S + kk * 32 + q * 8]);
#pragma unroll
      for (int nt = 0; nt < 8; ++nt) {
        bf16x8 a = *(const bf16x8*)(&WTl[(nt * 16 + ln) * WT_S + hh * 64 + kk * 32 + q * 8]);
        acc[0][nt] = __builtin_amdgcn_mfma_f32_16x16x32_bf16(a, b0, acc[0][nt], 0, 0, 0);
        acc[1][nt] = __builtin_amdgcn_mfma_f32_16x16x32_bf16(a, b1, acc[1][nt], 0, 0, 0);
      }
    }
  }
  // epilogue: lane holds D for m = m0b + w*32 + mt*16 + ln, n = nt*16 + q*4 + reg
  // fp8 pack: 4 consecutive channels -> 1 uint at uint-index nt*4 + q
#pragma unroll
  for (int mt = 0; mt < 2; ++mt) {
    int m = m0b + w * 32 + mt * 16 + ln;
    if (m < NN) {
      uint* yp = Yr + (size_t)m * 32;
#pragma unroll
      for (int nt = 0; nt < 8; ++nt) {
        f32x4 v = acc[mt][nt];
        uint u = __builtin_amdgcn_cvt_pk_fp8_f32(v[0], v[1], 0u, false);
        u = __builtin_amdgcn_cvt_pk_fp8_f32(v[2], v[3], u, true);
        yp[nt * 4 + q] = u;
      }
    }
  }
}

// ---------------- aggregation: 1 wave per node, 2 channels/lane (fp8 gather) ----------------
__global__ __launch_bounds__(256) void k_agg(const ushort* __restrict__ xw,
                                             const int* __restrict__ rp,
                                             const int* __restrict__ ci,
                                             const float* __restrict__ isd,
                                             const float* __restrict__ bias,
                                             uint* __restrict__ hout, int relu_flag) {
  int w = threadIdx.x >> 6;
  int lane = threadIdx.x & 63;
  int i = blockIdx.x * 4 + w;
  float aLo = bias[lane * 2] + bias[DD + lane * 2];
  float aHi = bias[lane * 2 + 1] + bias[DD + lane * 2 + 1];
#pragma unroll
  for (int r = 0; r < RR; ++r) {
    const ushort* xwr = xw + (size_t)r * NN * 64;  // fp8 row = 64 ushorts
    const float* isdr = isd + r * NN;
    const int* cir = ci + (size_t)r * EE;
    float di = isdr[i];
    {
      f32x2 v = __builtin_amdgcn_cvt_pk_f32_fp8((uint)xwr[(size_t)i * 64 + lane], false);
      float dd = di * di;
      aLo += v[0] * dd;
      aHi += v[1] * dd;
    }
    int e0 = rp[r * (NN + 1) + i];
    int e1 = rp[r * (NN + 1) + i + 1];
    int e = e0;
    for (; e + 8 <= e1; e += 8) {
      int s[8];
      uint u[8];
      float wt[8];
#pragma unroll
      for (int j = 0; j < 8; ++j) s[j] = cir[e + j];
#pragma unroll
      for (int j = 0; j < 8; ++j) u[j] = (uint)xwr[(size_t)s[j] * 64 + lane];
#pragma unroll
      for (int j = 0; j < 8; ++j) wt[j] = isdr[s[j]] * di;
#pragma unroll
      for (int j = 0; j < 8; ++j) {
        f32x2 v = __builtin_amdgcn_cvt_pk_f32_fp8(u[j], false);
        aLo += v[0] * wt[j];
        aHi += v[1] * wt[j];
      }
    }
    for (; e < e1; ++e) {
      int s = cir[e];
      float wt = isdr[s] * di;
      f32x2 v = __builtin_amdgcn_cvt_pk_f32_fp8((uint)xwr[(size_t)s * 64 + lane], false);
      aLo += v[0] * wt;
      aHi += v[1] * wt;
    }
  }
  if (relu_flag) {
    aLo = fmaxf(aLo, 0.f);
    aHi = fmaxf(aHi, 0.f);
  }
  hout[(size_t)i * 64 + lane] = (uint)f2b(aLo) | ((uint)f2b(aHi) << 16);
}

// ---------------- pooling (batch ids sorted), packed bf16 input ----------------
// 32 nodes/block (1563 blocks) + next-iter prefetch: latency-parallel, segment
// flushes only at group boundaries (~1600 total across the grid).
#define PCHUNK 32
__global__ __launch_bounds__(64) void k_pool(const uint* __restrict__ h,
                                             const int* __restrict__ batch,
                                             float* __restrict__ sums,
                                             int* __restrict__ counts) {
  int lane = threadIdx.x;
  int n0 = blockIdx.x * PCHUNK;
  int n1 = n0 + PCHUNK;
  if (n1 > NN) n1 = NN;
  if (n0 >= NN) return;
  float aLo = 0.f, aHi = 0.f;
  int cnt = 0;
  int g = batch[n0];                       // group of current node
  uint u = h[(size_t)n0 * 64 + lane];      // row of current node
  for (int n = n0; n < n1; ++n) {
    uint unext = 0;
    int gnext = g;
    if (n + 1 < n1) {                      // prefetch next row + group id
      unext = h[(size_t)(n + 1) * 64 + lane];
      gnext = batch[n + 1];
    }
    aLo += blo(u);
    aHi += bhi(u);
    cnt++;
    if (n + 1 < n1 && gnext != g) {        // flush at group boundary
      atomicAdd(&sums[g * DD + lane * 2], aLo);
      atomicAdd(&sums[g * DD + lane * 2 + 1], aHi);
      if (lane == 0) atomicAdd(&counts[g], cnt);
      aLo = 0.f; aHi = 0.f; cnt = 0;
      g = gnext;
    }
    u = unext;
  }
  atomicAdd(&sums[g * DD + lane * 2], aLo);
  atomicAdd(&sums[g * DD + lane * 2 + 1], aHi);
  if (lane == 0) atomicAdd(&counts[g], cnt);
}

__global__ __launch_bounds__(512) void k_final(const float* __restrict__ sums,
                                               const int* __restrict__ counts,
                                               const float* __restrict__ lin_w,
                                               const float* __restrict__ lin_b,
                                               float* __restrict__ out) {
  int t = threadIdx.x;  // 512 = 64 graphs x 8 classes
  int g = t >> 3, co = t & 7;
  float cnt = (float)counts[g];
  if (cnt < 1.f) cnt = 1.f;
  float inv = 1.f / cnt;
  float v = lin_b[co];
  for (int d = 0; d < DD; ++d) v += (sums[g * DD + d] * inv) * lin_w[d * CCLS + co];
  out[t] = v;
}

extern "C" void kernel_launch(void* const* d_in, const int* in_sizes, int n_in,
                              void* d_out, int out_size, void* d_ws, size_t ws_size,
                              hipStream_t stream) {
  (void)in_sizes; (void)n_in; (void)out_size; (void)ws_size;
  const float* x     = (const float*)d_in[0];
  const float* W     = (const float*)d_in[1];
  const float* b     = (const float*)d_in[2];
  const float* lin_w = (const float*)d_in[3];
  const float* lin_b = (const float*)d_in[4];
  const int*   EI    = (const int*)d_in[5];
  const int*   batch = (const int*)d_in[6];
  float* out = (float*)d_out;

  char* ws = (char*)d_ws;
  uint*   xw    = (uint*)(ws + OFF_XW);       // fp8 table
  uint*   h1    = (uint*)(ws + OFF_H1);       // bf16 packed
  ushort* WbfT  = (ushort*)(ws + OFF_WBT);
  float*  isd   = (float*)(ws + OFF_ISD);
  int*    rp    = (int*)(ws + OFF_RP);
  int*    ci    = (int*)(ws + OFF_CI);
  uint*   bdata = (uint*)(ws + OFF_BD);
  char*   zb    = ws + OFF_ZERO;
  int*    gcur  = (int*)(zb + ZO_GCUR);
  float*  sums  = (float*)(zb + ZO_SUM);
  int*    counts= (int*)(zb + ZO_CNT);

  (void)hipMemsetAsync(zb, 0, ZERO_BYTES, stream);

  k_wprep<<<256, 256, 0, stream>>>(W, WbfT);
  k_part<<<dim3((EE + 4095) / 4096, RR), 256, 0, stream>>>(EI, gcur, bdata);
  k_csr<<<dim3(NBUK, RR), 256, 0, stream>>>(bdata, gcur, isd, rp, ci);

  for (int l = 0; l < LL; ++l) {
    const ushort* WTl_g = WbfT + (size_t)l * RR * DD * DD;
    if (l == 0)
      k_gemm<0><<<dim3((NN + 127) / 128, RR), 256, 0, stream>>>((const void*)x, WTl_g, xw);
    else
      k_gemm<1><<<dim3((NN + 127) / 128, RR), 256, 0, stream>>>((const void*)h1, WTl_g, xw);
    k_agg<<<(NN + 3) / 4, 256, 0, stream>>>((const ushort*)xw, rp, ci, isd,
                                            b + (size_t)l * RR * DD, h1,
                                            (l < LL - 1) ? 1 : 0);
  }
  k_pool<<<(NN + PCHUNK - 1) / PCHUNK, 64, 0, stream>>>(h1, batch, sums, counts);
  k_final<<<1, GG * CCLS, 0, stream>>>(sums, counts, lin_w, lin_b, out);
}

// Round 6
// 256.958 us; speedup vs baseline: 2.5967x; 1.1586x over previous
//
#include <hip/hip_runtime.h>
#include <math.h>

#define NN 50000
#define EE 800000
#define RR 2
#define LL 2
#define DD 128
#define GG 64
#define CCLS 8
#define NBUK 196     // buckets of 256 dst nodes: bucket = dst >> 8
#define BCAP 6144    // max edges per bucket (mean 4082, sigma 64)

typedef unsigned int uint;
typedef unsigned short ushort;
typedef short bf16x8 __attribute__((ext_vector_type(8)));
typedef float f32x4 __attribute__((ext_vector_type(4)));
typedef float f32x2 __attribute__((ext_vector_type(2)));

// ---------------- workspace layout (bytes) ----------------
#define OFF_XW    ((size_t)0)           // [2][N][128] fp8 e4m3 (isd-scaled) 12,800,000
#define OFF_H1    ((size_t)12800000)    // [N][64] uint (packed bf16)      12,800,000
#define OFF_WBT   ((size_t)25600000)    // [L][R][128][128] bf16              131,072
#define OFF_ISD   ((size_t)25731072)    // [2][N] f32                         400,000
#define OFF_RP    ((size_t)26131072)    // [2][N+1] i32                       400,064
#define OFF_CI    ((size_t)26531136)    // [2][E] i32                       6,400,000
#define OFF_BD    ((size_t)32931136)    // [2][196][6144] uint              9,633,792
#define OFF_ZERO  ((size_t)42564928)
// zero region internal offsets (bytes)
#define ZO_GCUR 0        // [2][196] i32 bucket counters (1568 B, pad 1600)
#define ZO_SUM  1600     // [G][D] f32 (32768 B)
#define ZO_CNT  34368    // [G] i32 (256 B)
#define ZERO_BYTES 34624

static __device__ __forceinline__ ushort f2b(float f) {
  uint u = __float_as_uint(f);
  uint r = (u + 0x7fffu + ((u >> 16) & 1u)) >> 16;
  return (ushort)r;
}
static __device__ __forceinline__ float blo(uint u) { return __uint_as_float(u << 16); }
static __device__ __forceinline__ float bhi(uint u) { return __uint_as_float(u & 0xffff0000u); }

// ---------------- W prep: fp32 W[l][r][k][n] -> bf16 WbfT[l][r][n][k] ----------------
__global__ __launch_bounds__(256) void k_wprep(const float* __restrict__ W,
                                               ushort* __restrict__ WT) {
  int idx = blockIdx.x * 256 + threadIdx.x;  // 65536 total
  int lr = idx >> 14;
  int rem = idx & 16383;
  int n = rem >> 7, k = rem & 127;
  WT[lr * 16384 + n * 128 + k] = f2b(W[lr * 16384 + k * 128 + n]);
}

// ---------------- phase 1: partition edges into dst buckets (coalesced) ----------------
__global__ __launch_bounds__(256) void k_part(const int* __restrict__ EI,
                                              int* __restrict__ gcur,
                                              uint* __restrict__ bdata) {
  __shared__ int hist[256];   // bucket counts -> stage-exclusive offsets
  __shared__ int sbase[256];  // scan scratch
  __shared__ int gbase[256];  // global reservation base per bucket
  __shared__ int lcur[256];
  __shared__ uint stage[4096];
  __shared__ unsigned char bstage[4096];
  const int r = blockIdx.y;
  const int t = threadIdx.x;
  const int e0 = blockIdx.x * 4096;
  const int cnt = min(4096, EE - e0);
  hist[t] = 0;
  lcur[t] = 0;
  __syncthreads();

  int src[16], dst[16];
  bool val[4];
#pragma unroll
  for (int j = 0; j < 4; ++j) {
    int i4 = (j * 256 + t) * 4;
    val[j] = (i4 < cnt);
    if (val[j]) {
      int4 s4 = *(const int4*)(EI + (size_t)r * 2 * EE + e0 + i4);
      int4 d4 = *(const int4*)(EI + (size_t)r * 2 * EE + EE + e0 + i4);
      src[j * 4 + 0] = s4.x; src[j * 4 + 1] = s4.y; src[j * 4 + 2] = s4.z; src[j * 4 + 3] = s4.w;
      dst[j * 4 + 0] = d4.x; dst[j * 4 + 1] = d4.y; dst[j * 4 + 2] = d4.z; dst[j * 4 + 3] = d4.w;
#pragma unroll
      for (int i = 0; i < 4; ++i) atomicAdd(&hist[dst[j * 4 + i] >> 8], 1);
    }
  }
  __syncthreads();
  int hv = hist[t];
  if (t < NBUK && hv > 0)
    gbase[t] = atomicAdd(&gcur[r * NBUK + t], hv);
  else
    gbase[t] = 0;
  sbase[t] = hv;
  __syncthreads();
  for (int off = 1; off < 256; off <<= 1) {
    int u = (t >= off) ? sbase[t - off] : 0;
    __syncthreads();
    sbase[t] += u;
    __syncthreads();
  }
  int incl = sbase[t];
  hist[t] = incl - hv;  // exclusive stage offset
  __syncthreads();
#pragma unroll
  for (int j = 0; j < 4; ++j) {
    if (val[j]) {
#pragma unroll
      for (int i = 0; i < 4; ++i) {
        int d = dst[j * 4 + i];
        int b = d >> 8;
        int p = atomicAdd(&lcur[b], 1);
        int pos = hist[b] + p;
        stage[pos] = ((uint)src[j * 4 + i] << 8) | (uint)(d & 255);
        bstage[pos] = (unsigned char)b;
      }
    }
  }
  __syncthreads();
  for (int s = t; s < cnt; s += 256) {
    int b = (int)bstage[s];
    bdata[(size_t)(r * NBUK + b) * BCAP + gbase[b] + (s - hist[b])] = stage[s];
  }
}

// ---------------- phase 2: per-bucket CSR (deg, isd, rp, ci) all coalesced ----------------
__global__ __launch_bounds__(256) void k_csr(const uint* __restrict__ bdata,
                                             const int* __restrict__ gcur,
                                             float* __restrict__ isd,
                                             int* __restrict__ rp,
                                             int* __restrict__ ci) {
  __shared__ int lcnt[256];
  __shared__ int lrp[256];
  __shared__ int lcur[256];
  __shared__ int cstage[BCAP];
  __shared__ int basesh;
  const int b = blockIdx.x;
  const int r = blockIdx.y;
  const int t = threadIdx.x;
  const int cnt = gcur[r * NBUK + b];
  // bucket base = prefix sum of gcur[r][0..b-1] (NBUK <= 256: 1 elem/thread)
  lcnt[t] = (t < b) ? gcur[r * NBUK + t] : 0;
  __syncthreads();
  for (int off = 128; off > 0; off >>= 1) {
    if (t < off) lcnt[t] += lcnt[t + off];
    __syncthreads();
  }
  if (t == 0) basesh = lcnt[0];
  __syncthreads();
  const int base = basesh;
  const uint* bd = bdata + (size_t)(r * NBUK + b) * BCAP;
  __syncthreads();
  lcnt[t] = 0;
  lcur[t] = 0;
  __syncthreads();
  for (int s = t; s < cnt; s += 256) {
    uint pr = bd[s];
    atomicAdd(&lcnt[pr & 255u], 1);
  }
  __syncthreads();
  int deg = lcnt[t];
  lrp[t] = deg;
  __syncthreads();
  for (int off = 1; off < 256; off <<= 1) {
    int u = (t >= off) ? lrp[t - off] : 0;
    __syncthreads();
    lrp[t] += u;
    __syncthreads();
  }
  int incl = lrp[t];
  __syncthreads();
  lrp[t] = incl - deg;  // exclusive
  __syncthreads();
  int node = b * 256 + t;
  if (node < NN) {
    isd[r * NN + node] = rsqrtf((float)(deg + 1));
    rp[r * (NN + 1) + node] = base + lrp[t];
  }
  if (b == NBUK - 1 && t == 0) rp[r * (NN + 1) + NN] = EE;
  for (int s = t; s < cnt; s += 256) {
    uint pr = bd[s];
    int j = (int)(pr & 255u);
    int p = atomicAdd(&lcur[j], 1);
    cstage[lrp[j] + p] = (int)(pr >> 8);
  }
  __syncthreads();
  for (int s = t; s < cnt; s += 256) ci[(size_t)r * EE + base + s] = cstage[s];
}

// ---------------- MFMA GEMM: xw'[r][m][:] = (X[m][:] @ W[r]) * isd[r][m], fp8 out ----------------
#define AL_S 72    // 64+8 bf16 row stride
#define WT_S 136   // 128+8 bf16 row stride
template <int IN_BF16>
__global__ __launch_bounds__(256) void k_gemm(const void* __restrict__ Xv,
                                              const ushort* __restrict__ WTg,
                                              const float* __restrict__ isd,
                                              uint* __restrict__ Y) {
  __shared__ ushort WTl[128 * WT_S];
  __shared__ ushort Al[128 * AL_S];
  const int r = blockIdx.y;
  const int m0b = blockIdx.x * 128;
  const int t = threadIdx.x;
  const int w = t >> 6, L = t & 63, q = L >> 4, ln = L & 15;
  uint* Yr = Y + (size_t)r * NN * 32;   // fp8 row = 32 uints
  const ushort* WTr = WTg + (size_t)r * 16384;

#pragma unroll
  for (int i = 0; i < 8; ++i) {
    int g = t + i * 256;
    int n = g >> 4, k0 = (g & 15) * 8;
    *(uint4*)(&WTl[n * WT_S + k0]) = *(const uint4*)(WTr + n * 128 + k0);
  }

  f32x4 acc[2][8];
#pragma unroll
  for (int mt = 0; mt < 2; ++mt)
#pragma unroll
    for (int nt = 0; nt < 8; ++nt) {
      acc[mt][nt][0] = 0.f; acc[mt][nt][1] = 0.f;
      acc[mt][nt][2] = 0.f; acc[mt][nt][3] = 0.f;
    }

  for (int hh = 0; hh < 2; ++hh) {
    __syncthreads();
    {
      int row = t >> 1, ch = t & 1;
      int gm = m0b + row;
      ushort* dst = &Al[row * AL_S + ch * 32];
      if (gm < NN) {
        if (IN_BF16) {
          const uint4* xp = (const uint4*)((const ushort*)Xv + (size_t)gm * 128 + hh * 64 + ch * 32);
#pragma unroll
          for (int j = 0; j < 4; ++j) ((uint4*)dst)[j] = xp[j];
        } else {
          const float4* xp = (const float4*)((const float*)Xv + (size_t)gm * 128 + hh * 64 + ch * 32);
          ushort tmp[32];
#pragma unroll
          for (int j = 0; j < 8; ++j) {
            float4 v = xp[j];
            tmp[j * 4 + 0] = f2b(v.x); tmp[j * 4 + 1] = f2b(v.y);
            tmp[j * 4 + 2] = f2b(v.z); tmp[j * 4 + 3] = f2b(v.w);
          }
#pragma unroll
          for (int j = 0; j < 4; ++j) ((uint4*)dst)[j] = ((uint4*)tmp)[j];
        }
      } else {
        uint4 z = make_uint4(0, 0, 0, 0);
#pragma unroll
        for (int j = 0; j < 4; ++j) ((uint4*)dst)[j] = z;
      }
    }
    __syncthreads();
#pragma unroll
    for (int kk = 0; kk < 2; ++kk) {
      bf16x8 b0 = *(const bf16x8*)(&Al[(w * 32 + ln) * AL_S + kk * 32 + q * 8]);
      bf16x8 b1 = *(const bf16x8*)(&Al[(w * 32 + 16 + ln) * AL_S + kk * 32 + q * 8]);
#pragma unroll
      for (int nt = 0; nt < 8; ++nt) {
        bf16x8 a = *(const bf16x8*)(&WTl[(nt * 16 + ln) * WT_S + hh * 64 + kk * 32 + q * 8]);
        acc[0][nt] = __builtin_amdgcn_mfma_f32_16x16x32_bf16(a, b0, acc[0][nt], 0, 0, 0);
        acc[1][nt] = __builtin_amdgcn_mfma_f32_16x16x32_bf16(a, b1, acc[1][nt], 0, 0, 0);
      }
    }
  }
  // epilogue: lane holds D for m = m0b + w*32 + mt*16 + ln, n = nt*16 + q*4 + reg
  // scale by isd[r][m], then fp8 pack: byte n of row = channel n
#pragma unroll
  for (int mt = 0; mt < 2; ++mt) {
    int m = m0b + w * 32 + mt * 16 + ln;
    if (m < NN) {
      float sc = isd[r * NN + m];
      uint* yp = Yr + (size_t)m * 32;
#pragma unroll
      for (int nt = 0; nt < 8; ++nt) {
        f32x4 v = acc[mt][nt];
        uint u = __builtin_amdgcn_cvt_pk_fp8_f32(v[0] * sc, v[1] * sc, 0u, false);
        u = __builtin_amdgcn_cvt_pk_fp8_f32(v[2] * sc, v[3] * sc, u, true);
        yp[nt * 4 + q] = u;
      }
    }
  }
}

// ---------------- aggregation: 1 wave/node, 8 edges in flight, uint4 gathers ----------------
// lane = g*8 + c: g = edge slot (0..7), c = channel quad (16 fp8 channels = 1 uint4).
// out[i] = sum_r di_r * (sum_e xw'[src_e] + xw'[i]) + bias   (xw' is isd-prescaled)
__global__ __launch_bounds__(256) void k_agg(const uint4* __restrict__ xw4,
                                             const int* __restrict__ rp,
                                             const int* __restrict__ ci,
                                             const float* __restrict__ isd,
                                             const float* __restrict__ bias,
                                             uint* __restrict__ hout, int relu_flag) {
  const int w = threadIdx.x >> 6;
  const int lane = threadIdx.x & 63;
  const int g = lane >> 3, c = lane & 7;
  const int i = blockIdx.x * 4 + w;

  float tot[16];
#pragma unroll
  for (int k = 0; k < 16; ++k) tot[k] = 0.f;

#pragma unroll
  for (int r = 0; r < RR; ++r) {
    const uint4* xwr = xw4 + (size_t)r * NN * 8;  // 8 uint4 per row
    const int* cir = ci + (size_t)r * EE;
    const float di = isd[r * NN + i];
    const int e0 = rp[r * (NN + 1) + i];
    const int cnt = rp[r * (NN + 1) + i + 1] - e0;
    const int total = cnt + 1;  // + self (virtual edge idx == cnt, s = i)

    float acc[16];
#pragma unroll
    for (int k = 0; k < 16; ++k) acc[k] = 0.f;

    int s_cur = (g < cnt) ? cir[e0 + g] : i;
    for (int base = 0; base < total; base += 8) {
      int idxn = base + 8 + g;
      int s_next = (idxn < cnt) ? cir[e0 + idxn] : i;  // prefetch next slot's index
      if (base + g < total) {
        uint4 u = xwr[(size_t)s_cur * 8 + c];
        f32x2 v;
        v = __builtin_amdgcn_cvt_pk_f32_fp8(u.x, false); acc[0] += v[0];  acc[1] += v[1];
        v = __builtin_amdgcn_cvt_pk_f32_fp8(u.x, true);  acc[2] += v[0];  acc[3] += v[1];
        v = __builtin_amdgcn_cvt_pk_f32_fp8(u.y, false); acc[4] += v[0];  acc[5] += v[1];
        v = __builtin_amdgcn_cvt_pk_f32_fp8(u.y, true);  acc[6] += v[0];  acc[7] += v[1];
        v = __builtin_amdgcn_cvt_pk_f32_fp8(u.z, false); acc[8] += v[0];  acc[9] += v[1];
        v = __builtin_amdgcn_cvt_pk_f32_fp8(u.z, true);  acc[10] += v[0]; acc[11] += v[1];
        v = __builtin_amdgcn_cvt_pk_f32_fp8(u.w, false); acc[12] += v[0]; acc[13] += v[1];
        v = __builtin_amdgcn_cvt_pk_f32_fp8(u.w, true);  acc[14] += v[0]; acc[15] += v[1];
      }
      s_cur = s_next;
    }
#pragma unroll
    for (int k = 0; k < 16; ++k) tot[k] = fmaf(di, acc[k], tot[k]);
  }

  // reduce over the 8 edge slots (lane bits 3,4,5)
#pragma unroll
  for (int mask = 8; mask <= 32; mask <<= 1) {
#pragma unroll
    for (int k = 0; k < 16; ++k) tot[k] += __shfl_xor(tot[k], mask);
  }

  // lanes g<2 write: lane (g,c) stores channels [c*16 + g*8, +8) as 4 packed uints
  if (g < 2) {
    int ch0 = c * 16 + g * 8;
    const float4* bp = (const float4*)(bias + ch0);
    const float4* bq = (const float4*)(bias + DD + ch0);
    float4 b0 = bp[0], b1 = bp[1], b2 = bq[0], b3 = bq[1];
    float o[8];
#pragma unroll
    for (int j = 0; j < 8; ++j) o[j] = (g == 0) ? tot[j] : tot[8 + j];
    o[0] += b0.x + b2.x; o[1] += b0.y + b2.y; o[2] += b0.z + b2.z; o[3] += b0.w + b2.w;
    o[4] += b1.x + b3.x; o[5] += b1.y + b3.y; o[6] += b1.z + b3.z; o[7] += b1.w + b3.w;
    if (relu_flag) {
#pragma unroll
      for (int j = 0; j < 8; ++j) o[j] = fmaxf(o[j], 0.f);
    }
    uint4 pk;
    pk.x = (uint)f2b(o[0]) | ((uint)f2b(o[1]) << 16);
    pk.y = (uint)f2b(o[2]) | ((uint)f2b(o[3]) << 16);
    pk.z = (uint)f2b(o[4]) | ((uint)f2b(o[5]) << 16);
    pk.w = (uint)f2b(o[6]) | ((uint)f2b(o[7]) << 16);
    ((uint4*)(hout + (size_t)i * 64))[c * 2 + g] = pk;
  }
}

// ---------------- pooling (batch ids sorted), packed bf16 input ----------------
#define PCHUNK 32
__global__ __launch_bounds__(64) void k_pool(const uint* __restrict__ h,
                                             const int* __restrict__ batch,
                                             float* __restrict__ sums,
                                             int* __restrict__ counts) {
  int lane = threadIdx.x;
  int n0 = blockIdx.x * PCHUNK;
  int n1 = n0 + PCHUNK;
  if (n1 > NN) n1 = NN;
  if (n0 >= NN) return;
  float aLo = 0.f, aHi = 0.f;
  int cnt = 0;
  int g = batch[n0];
  uint u = h[(size_t)n0 * 64 + lane];
  for (int n = n0; n < n1; ++n) {
    uint unext = 0;
    int gnext = g;
    if (n + 1 < n1) {
      unext = h[(size_t)(n + 1) * 64 + lane];
      gnext = batch[n + 1];
    }
    aLo += blo(u);
    aHi += bhi(u);
    cnt++;
    if (n + 1 < n1 && gnext != g) {
      atomicAdd(&sums[g * DD + lane * 2], aLo);
      atomicAdd(&sums[g * DD + lane * 2 + 1], aHi);
      if (lane == 0) atomicAdd(&counts[g], cnt);
      aLo = 0.f; aHi = 0.f; cnt = 0;
      g = gnext;
    }
    u = unext;
  }
  atomicAdd(&sums[g * DD + lane * 2], aLo);
  atomicAdd(&sums[g * DD + lane * 2 + 1], aHi);
  if (lane == 0) atomicAdd(&counts[g], cnt);
}

__global__ __launch_bounds__(512) void k_final(const float* __restrict__ sums,
                                               const int* __restrict__ counts,
                                               const float* __restrict__ lin_w,
                                               const float* __restrict__ lin_b,
                                               float* __restrict__ out) {
  int t = threadIdx.x;  // 512 = 64 graphs x 8 classes
  int g = t >> 3, co = t & 7;
  float cnt = (float)counts[g];
  if (cnt < 1.f) cnt = 1.f;
  float inv = 1.f / cnt;
  float v = lin_b[co];
  for (int d = 0; d < DD; ++d) v += (sums[g * DD + d] * inv) * lin_w[d * CCLS + co];
  out[t] = v;
}

extern "C" void kernel_launch(void* const* d_in, const int* in_sizes, int n_in,
                              void* d_out, int out_size, void* d_ws, size_t ws_size,
                              hipStream_t stream) {
  (void)in_sizes; (void)n_in; (void)out_size; (void)ws_size;
  const float* x     = (const float*)d_in[0];
  const float* W     = (const float*)d_in[1];
  const float* b     = (const float*)d_in[2];
  const float* lin_w = (const float*)d_in[3];
  const float* lin_b = (const float*)d_in[4];
  const int*   EI    = (const int*)d_in[5];
  const int*   batch = (const int*)d_in[6];
  float* out = (float*)d_out;

  char* ws = (char*)d_ws;
  uint*   xw    = (uint*)(ws + OFF_XW);       // fp8 table (isd-prescaled)
  uint*   h1    = (uint*)(ws + OFF_H1);       // bf16 packed
  ushort* WbfT  = (ushort*)(ws + OFF_WBT);
  float*  isd   = (float*)(ws + OFF_ISD);
  int*    rp    = (int*)(ws + OFF_RP);
  int*    ci    = (int*)(ws + OFF_CI);
  uint*   bdata = (uint*)(ws + OFF_BD);
  char*   zb    = ws + OFF_ZERO;
  int*    gcur  = (int*)(zb + ZO_GCUR);
  float*  sums  = (float*)(zb + ZO_SUM);
  int*    counts= (int*)(zb + ZO_CNT);

  (void)hipMemsetAsync(zb, 0, ZERO_BYTES, stream);

  k_wprep<<<256, 256, 0, stream>>>(W, WbfT);
  k_part<<<dim3((EE + 4095) / 4096, RR), 256, 0, stream>>>(EI, gcur, bdata);
  k_csr<<<dim3(NBUK, RR), 256, 0, stream>>>(bdata, gcur, isd, rp, ci);

  for (int l = 0; l < LL; ++l) {
    const ushort* WTl_g = WbfT + (size_t)l * RR * DD * DD;
    if (l == 0)
      k_gemm<0><<<dim3((NN + 127) / 128, RR), 256, 0, stream>>>((const void*)x, WTl_g, isd, xw);
    else
      k_gemm<1><<<dim3((NN + 127) / 128, RR), 256, 0, stream>>>((const void*)h1, WTl_g, isd, xw);
    k_agg<<<(NN + 3) / 4, 256, 0, stream>>>((const uint4*)xw, rp, ci, isd,
                                            b + (size_t)l * RR * DD, h1,
                                            (l < LL - 1) ? 1 : 0);
  }
  k_pool<<<(NN + PCHUNK - 1) / PCHUNK, 64, 0, stream>>>(h1, batch, sums, counts);
  k_final<<<1, GG * CCLS, 0, stream>>>(sums, counts, lin_w, lin_b, out);
}